// Round 6
// baseline (823.173 us; speedup 1.0000x reference)
//
#include <hip/hip_runtime.h>
#include <hip/hip_fp16.h>
#include <math.h>

#define LEAKY 0.2f
#define BP 6                     // nodes per bucket = 64
#define BSZ 64
#define NBUK_MAX 2048

typedef _Float16 f16x8 __attribute__((ext_vector_type(8)));
typedef float f32x4 __attribute__((ext_vector_type(4)));

union H2 { __half2 h; int i; };
union H8 { __half2 h[4]; float4 f; };
union H4 { __half2 h[2]; float2 f; };

__device__ inline __half2 shfl_xor_h2(__half2 v, int m) {
    H2 u; u.h = v;
    u.i = __shfl_xor(u.i, m);
    return u.h;
}

// ---------------- kinit: khist (blocks 0..255) + W1 transpose (256..383) ----------------
__global__ __launch_bounds__(256) void kinit(const int* __restrict__ dst,
                                             int* __restrict__ bhist,
                                             int E, int nbuk,
                                             const float* __restrict__ W1,
                                             __half* __restrict__ W1t) {
    if (blockIdx.x < 256) {
        __shared__ int hist[NBUK_MAX];
        int t = threadIdx.x;
        for (int i = t; i < nbuk; i += 256) hist[i] = 0;
        __syncthreads();
        for (int e = blockIdx.x * 256 + t; e < E; e += 65536)
            atomicAdd(&hist[dst[e] >> BP], 1);
        __syncthreads();
        for (int i = t; i < nbuk; i += 256) {
            int v = hist[i];
            if (v) atomicAdd(&bhist[i], v);
        }
    } else {
        int idx = (blockIdx.x - 256) * 256 + threadIdx.x;
        if (idx < 32768) {
            int n = idx >> 8, k = idx & 255;              // W1t[128][256]
            W1t[idx] = __float2half(W1[k * 128 + n]);
        }
    }
}

// single-block exclusive scan of bucket counts -> bbase, bcur
__global__ __launch_bounds__(1024) void bscan(const int* __restrict__ bhist,
                                              int* __restrict__ bbase,
                                              int* __restrict__ bcur, int nbuk) {
    __shared__ int s[1024];
    int t = threadIdx.x;
    int v[4]; int sum = 0;
    #pragma unroll
    for (int i = 0; i < 4; ++i) {
        int idx = t * 4 + i;
        v[i] = (idx < nbuk) ? bhist[idx] : 0;
        sum += v[i];
    }
    s[t] = sum; __syncthreads();
    for (int off = 1; off < 1024; off <<= 1) {
        int a = (t >= off) ? s[t - off] : 0;
        __syncthreads();
        s[t] += a;
        __syncthreads();
    }
    int run = (t > 0) ? s[t - 1] : 0;
    #pragma unroll
    for (int i = 0; i < 4; ++i) {
        int idx = t * 4 + i;
        if (idx < nbuk) { bbase[idx] = run; bcur[idx] = run; run += v[i]; }
    }
    if (t == 1023) bbase[nbuk] = s[1023];
}

// block-local binning scatter
__global__ __launch_bounds__(256) void kscatter2(const int* __restrict__ src,
                                                 const int* __restrict__ dst,
                                                 int* __restrict__ bcur,
                                                 int* __restrict__ ebuf,
                                                 int E, int nbuk, int chunk) {
    __shared__ int hist[NBUK_MAX];
    int t = threadIdx.x;
    int base = blockIdx.x * chunk;
    int end = min(base + chunk, E);
    for (int i = t; i < nbuk; i += 256) hist[i] = 0;
    __syncthreads();
    for (int e = base + t; e < end; e += 256)
        atomicAdd(&hist[dst[e] >> BP], 1);
    __syncthreads();
    for (int i = t; i < nbuk; i += 256) {
        int c = hist[i];
        hist[i] = c ? atomicAdd(&bcur[i], c) : 0;
    }
    __syncthreads();
    for (int e = base + t; e < end; e += 256) {
        int d = dst[e];
        int pos = atomicAdd(&hist[d >> BP], 1);
        ebuf[pos] = ((d & (BSZ - 1)) << 17) | src[e];
    }
}

// merged count+scan+place: per-bucket counts -> rowptr + dis, then place into col.
// Second ebuf pass hits L1/L2 (avg bucket = 8 KB).
__global__ __launch_bounds__(256) void kbuild(const int* __restrict__ ebuf,
                                              const int* __restrict__ bbase,
                                              int* __restrict__ rowptr,
                                              float* __restrict__ dis,
                                              int* __restrict__ col, int N) {
    __shared__ int h[BSZ];
    __shared__ int cur[BSZ];
    int b = blockIdx.x, t = threadIdx.x;
    if (t < BSZ) h[t] = 0;
    __syncthreads();
    int beg = bbase[b], end = bbase[b + 1];
    for (int j = beg + t; j < end; j += 256)
        atomicAdd(&h[(ebuf[j] >> 17) & (BSZ - 1)], 1);
    __syncthreads();
    if (t < BSZ) {                      // threads 0..63 = wave 0
        int node = b * BSZ + t;
        int c = (node < N) ? h[t] + 1 : 0;   // +1 self-loop
        int incl = c;
        #pragma unroll
        for (int off = 1; off < 64; off <<= 1) {
            int v = __shfl_up(incl, off);
            if (t >= off) incl += v;
        }
        int colbase = beg + b * BSZ;
        if (node < N) {
            int r = colbase + incl - c;
            rowptr[node] = r;
            dis[node] = rsqrtf((float)c);
            col[r] = node;              // self-loop first
            cur[t] = r + 1;
            if (node == N - 1) rowptr[N] = colbase + incl;
        }
    }
    __syncthreads();
    for (int j = beg + t; j < end; j += 256) {
        int v = ebuf[j];
        int p = atomicAdd(&cur[(v >> 17) & (BSZ - 1)], 1);
        col[p] = v & 0x1FFFF;
    }
}

// ---------------- GEMM1: [M,256]fp32 @ W1t[128,256]fp16 -> fp16, *= dis[row] ----------------
__global__ __launch_bounds__(256) void gemm1_mfma(
        const float* __restrict__ x, const __half* __restrict__ W1t,
        const float* __restrict__ dis, __half* __restrict__ C, int M) {
    int wave = threadIdx.x >> 6;
    int lane = threadIdx.x & 63;
    int m = lane & 15, q = lane >> 4;
    int row0 = (blockIdx.x * 4 + wave) * 16;
    int arow = row0 + m;
    bool aval = arow < M;
    const float* xr = x + (size_t)arow * 256 + q * 8;
    f32x4 acc[8];
    #pragma unroll
    for (int c = 0; c < 8; ++c) acc[c] = (f32x4){0.f, 0.f, 0.f, 0.f};
    for (int k0 = 0; k0 < 256; k0 += 32) {
        f16x8 a;
        if (aval) {
            float4 v0 = *(const float4*)(xr + k0);
            float4 v1 = *(const float4*)(xr + k0 + 4);
            a[0] = (_Float16)v0.x; a[1] = (_Float16)v0.y;
            a[2] = (_Float16)v0.z; a[3] = (_Float16)v0.w;
            a[4] = (_Float16)v1.x; a[5] = (_Float16)v1.y;
            a[6] = (_Float16)v1.z; a[7] = (_Float16)v1.w;
        } else {
            #pragma unroll
            for (int i = 0; i < 8; ++i) a[i] = (_Float16)0.f;
        }
        #pragma unroll
        for (int c = 0; c < 8; ++c) {
            f16x8 b = *(const f16x8*)(W1t + (size_t)(c * 16 + m) * 256 + k0 + q * 8);
            acc[c] = __builtin_amdgcn_mfma_f32_16x16x32_f16(a, b, acc[c], 0, 0, 0);
        }
    }
    float dw[4];
    #pragma unroll
    for (int r = 0; r < 4; ++r) {
        int rr = row0 + q * 4 + r;
        dw[r] = (rr < M) ? dis[rr] : 0.f;
    }
    #pragma unroll
    for (int c = 0; c < 8; ++c) {
        #pragma unroll
        for (int r = 0; r < 4; ++r) {
            int rr = row0 + q * 4 + r;
            if (rr < M)
                C[(size_t)rr * 128 + c * 16 + m] = __float2half(acc[c][r] * dw[r]);
        }
    }
}

// ---------------- prop128g2: work-stealing wave/node; W2 fragment in REGISTERS ----------------
// out = h2h[n][16] = dis[n] * ( leaky(dis[n]*sum + b1) @ W2 )
// Each wave pops 4-node chunks from a global cursor -> near-perfect balance with
// full residency; W2 fragment loaded once per thread. No LDS, register epilogue.
__global__ __launch_bounds__(256) void prop128g2(
        const __half* __restrict__ h, const int* __restrict__ rowptr,
        const int* __restrict__ col, const float* __restrict__ dis,
        const float* __restrict__ bias, const float* __restrict__ W2,
        __half* __restrict__ out, int N, int* __restrict__ wctr) {
    int lane = threadIdx.x & 63;
    int eo = lane >> 4;
    int q = lane & 15;
    // hoisted loop-invariant W2 fragment + bias
    const f32x4* __restrict__ W24 = (const f32x4*)W2;
    f32x4 wreg[8];
    #pragma unroll
    for (int f = 0; f < 8; ++f)
        wreg[f] = W24[(q * 8 + f) * 4 + eo];    // W2[q*8+f][eo*4 .. eo*4+3]
    const float4* b4 = (const float4*)bias;
    float4 bA = b4[q * 2];
    float4 bB = b4[q * 2 + 1];
    const float4* __restrict__ h4 = (const float4*)h;

    for (;;) {
        int base;
        if (lane == 0) base = atomicAdd(wctr, 4);
        base = __shfl(base, 0);
        if (base >= N) break;
        int nend = min(base + 4, N);
        for (int n = base; n < nend; ++n) {
            int beg = rowptr[n], end = rowptr[n + 1];
            __half2 acc[4];
            acc[0] = acc[1] = acc[2] = acc[3] = __float2half2_rn(0.f);
            int j = beg + eo;
            for (; j + 28 < end; j += 32) {     // 32 edges in flight per wave
                int s0 = col[j],      s1 = col[j + 4],  s2 = col[j + 8],  s3 = col[j + 12];
                int s4 = col[j + 16], s5 = col[j + 20], s6 = col[j + 24], s7 = col[j + 28];
                H8 u0, u1, u2, u3, u4, u5, u6, u7;
                u0.f = h4[(size_t)s0 * 16 + q];
                u1.f = h4[(size_t)s1 * 16 + q];
                u2.f = h4[(size_t)s2 * 16 + q];
                u3.f = h4[(size_t)s3 * 16 + q];
                u4.f = h4[(size_t)s4 * 16 + q];
                u5.f = h4[(size_t)s5 * 16 + q];
                u6.f = h4[(size_t)s6 * 16 + q];
                u7.f = h4[(size_t)s7 * 16 + q];
                #pragma unroll
                for (int i = 0; i < 4; ++i) acc[i] = __hadd2(acc[i], u0.h[i]);
                #pragma unroll
                for (int i = 0; i < 4; ++i) acc[i] = __hadd2(acc[i], u1.h[i]);
                #pragma unroll
                for (int i = 0; i < 4; ++i) acc[i] = __hadd2(acc[i], u2.h[i]);
                #pragma unroll
                for (int i = 0; i < 4; ++i) acc[i] = __hadd2(acc[i], u3.h[i]);
                #pragma unroll
                for (int i = 0; i < 4; ++i) acc[i] = __hadd2(acc[i], u4.h[i]);
                #pragma unroll
                for (int i = 0; i < 4; ++i) acc[i] = __hadd2(acc[i], u5.h[i]);
                #pragma unroll
                for (int i = 0; i < 4; ++i) acc[i] = __hadd2(acc[i], u6.h[i]);
                #pragma unroll
                for (int i = 0; i < 4; ++i) acc[i] = __hadd2(acc[i], u7.h[i]);
            }
            for (; j + 12 < end; j += 16) {
                int s0 = col[j], s1 = col[j + 4], s2 = col[j + 8], s3 = col[j + 12];
                H8 u0, u1, u2, u3;
                u0.f = h4[(size_t)s0 * 16 + q];
                u1.f = h4[(size_t)s1 * 16 + q];
                u2.f = h4[(size_t)s2 * 16 + q];
                u3.f = h4[(size_t)s3 * 16 + q];
                #pragma unroll
                for (int i = 0; i < 4; ++i) acc[i] = __hadd2(acc[i], u0.h[i]);
                #pragma unroll
                for (int i = 0; i < 4; ++i) acc[i] = __hadd2(acc[i], u1.h[i]);
                #pragma unroll
                for (int i = 0; i < 4; ++i) acc[i] = __hadd2(acc[i], u2.h[i]);
                #pragma unroll
                for (int i = 0; i < 4; ++i) acc[i] = __hadd2(acc[i], u3.h[i]);
            }
            for (; j + 4 < end; j += 8) {
                int s0 = col[j], s1 = col[j + 4];
                H8 u0, u1;
                u0.f = h4[(size_t)s0 * 16 + q];
                u1.f = h4[(size_t)s1 * 16 + q];
                #pragma unroll
                for (int i = 0; i < 4; ++i) acc[i] = __hadd2(acc[i], u0.h[i]);
                #pragma unroll
                for (int i = 0; i < 4; ++i) acc[i] = __hadd2(acc[i], u1.h[i]);
            }
            for (; j < end; j += 4) {
                int s = col[j];
                H8 u; u.f = h4[(size_t)s * 16 + q];
                #pragma unroll
                for (int i = 0; i < 4; ++i) acc[i] = __hadd2(acc[i], u.h[i]);
            }
            #pragma unroll
            for (int i = 0; i < 4; ++i) {
                acc[i] = __hadd2(acc[i], shfl_xor_h2(acc[i], 16));
                acc[i] = __hadd2(acc[i], shfl_xor_h2(acc[i], 32));
            }
            // --- fused epilogue: pure-register W2 projection ---
            float dn = dis[n];
            float2 f0 = __half22float2(acc[0]);
            float2 f1 = __half22float2(acc[1]);
            float2 f2 = __half22float2(acc[2]);
            float2 f3 = __half22float2(acc[3]);
            float xf[8];
            xf[0] = fmaf(dn, f0.x, bA.x); xf[1] = fmaf(dn, f0.y, bA.y);
            xf[2] = fmaf(dn, f1.x, bA.z); xf[3] = fmaf(dn, f1.y, bA.w);
            xf[4] = fmaf(dn, f2.x, bB.x); xf[5] = fmaf(dn, f2.y, bB.y);
            xf[6] = fmaf(dn, f3.x, bB.z); xf[7] = fmaf(dn, f3.y, bB.w);
            #pragma unroll
            for (int i = 0; i < 8; ++i) xf[i] = xf[i] > 0.f ? xf[i] : LEAKY * xf[i];
            float p0 = 0.f, p1 = 0.f, p2 = 0.f, p3 = 0.f;
            #pragma unroll
            for (int f = 0; f < 8; ++f) {
                p0 = fmaf(xf[f], wreg[f][0], p0);
                p1 = fmaf(xf[f], wreg[f][1], p1);
                p2 = fmaf(xf[f], wreg[f][2], p2);
                p3 = fmaf(xf[f], wreg[f][3], p3);
            }
            #pragma unroll
            for (int mm = 1; mm < 16; mm <<= 1) {   // reduce over 16 q-lanes
                p0 += __shfl_xor(p0, mm);
                p1 += __shfl_xor(p1, mm);
                p2 += __shfl_xor(p2, mm);
                p3 += __shfl_xor(p3, mm);
            }
            if (q == 0) {
                H4 w;
                w.h[0] = __floats2half2_rn(p0 * dn, p1 * dn);
                w.h[1] = __floats2half2_rn(p2 * dn, p3 * dn);
                ((float2*)out)[(size_t)n * 4 + eo] = w.f;
            }
        }
    }
}

// ---------------- prop16: 16 lanes/node, 2 slots x 8 lanes, 16 edges in flight ----------------
// h rows fp16 pre-scaled by dis[src]; output x2 = dis*leaky(dis*sum + b) (pre-scaled fp16)
__global__ __launch_bounds__(256) void prop16(
        const __half* __restrict__ h, const int* __restrict__ rowptr,
        const int* __restrict__ col, const float* __restrict__ dis,
        const float* __restrict__ bias, __half* __restrict__ outp, int N) {
    int t = blockIdx.x * 256 + threadIdx.x;
    int n = t >> 4;
    if (n >= N) return;
    int li = threadIdx.x & 15;
    int eo = li >> 3;
    int hq = li & 7;
    const int* __restrict__ h2i = (const int*)h;
    int beg = rowptr[n], end = rowptr[n + 1];
    __half2 acc = __float2half2_rn(0.f);
    int j = beg + eo;
    for (; j + 14 < end; j += 16) {     // 16 edges in flight per node
        H2 u0, u1, u2, u3, u4, u5, u6, u7;
        u0.i = h2i[(size_t)col[j]      * 8 + hq];
        u1.i = h2i[(size_t)col[j + 2]  * 8 + hq];
        u2.i = h2i[(size_t)col[j + 4]  * 8 + hq];
        u3.i = h2i[(size_t)col[j + 6]  * 8 + hq];
        u4.i = h2i[(size_t)col[j + 8]  * 8 + hq];
        u5.i = h2i[(size_t)col[j + 10] * 8 + hq];
        u6.i = h2i[(size_t)col[j + 12] * 8 + hq];
        u7.i = h2i[(size_t)col[j + 14] * 8 + hq];
        acc = __hadd2(acc, u0.h); acc = __hadd2(acc, u1.h);
        acc = __hadd2(acc, u2.h); acc = __hadd2(acc, u3.h);
        acc = __hadd2(acc, u4.h); acc = __hadd2(acc, u5.h);
        acc = __hadd2(acc, u6.h); acc = __hadd2(acc, u7.h);
    }
    for (; j + 6 < end; j += 8) {
        H2 u0, u1, u2, u3;
        u0.i = h2i[(size_t)col[j]     * 8 + hq];
        u1.i = h2i[(size_t)col[j + 2] * 8 + hq];
        u2.i = h2i[(size_t)col[j + 4] * 8 + hq];
        u3.i = h2i[(size_t)col[j + 6] * 8 + hq];
        acc = __hadd2(acc, u0.h); acc = __hadd2(acc, u1.h);
        acc = __hadd2(acc, u2.h); acc = __hadd2(acc, u3.h);
    }
    for (; j < end; j += 2) {
        H2 u; u.i = h2i[(size_t)col[j] * 8 + hq];
        acc = __hadd2(acc, u.h);
    }
    acc = __hadd2(acc, shfl_xor_h2(acc, 8));
    if (eo == 0) {
        float dn = dis[n];
        float2 f = __half22float2(acc);
        float ox = fmaf(dn, f.x, bias[hq * 2]);
        float oy = fmaf(dn, f.y, bias[hq * 2 + 1]);
        ox = ox > 0.f ? ox : LEAKY * ox;
        oy = oy > 0.f ? oy : LEAKY * oy;
        ox *= dn; oy *= dn;
        H2 w; w.h = __floats2half2_rn(ox, oy);
        ((int*)outp)[(size_t)n * 8 + hq] = w.i;
    }
}

// ---------------- prop16_gemm3: gather x2 -> p3 (registers) -> @W3 + b3 -> out ----------------
__global__ __launch_bounds__(256) void prop16_gemm3(
        const __half* __restrict__ h, const int* __restrict__ rowptr,
        const int* __restrict__ col, const float* __restrict__ dis,
        const float* __restrict__ W3, const float* __restrict__ b3,
        float* __restrict__ out, int N) {
    __shared__ float sw[640];
    __shared__ float sb[40];
    int t0 = threadIdx.x;
    for (int i = t0; i < 640; i += 256) sw[i] = W3[i];
    if (t0 < 40) sb[t0] = b3[t0];
    __syncthreads();
    int t = blockIdx.x * 256 + t0;
    int n = t >> 4;
    if (n >= N) return;
    int li = t0 & 15;
    int eo = li >> 3;
    int hq = li & 7;
    const int* __restrict__ h2i = (const int*)h;
    int beg = rowptr[n], end = rowptr[n + 1];
    __half2 acc = __float2half2_rn(0.f);
    int j = beg + eo;
    for (; j + 14 < end; j += 16) {
        H2 u0, u1, u2, u3, u4, u5, u6, u7;
        u0.i = h2i[(size_t)col[j]      * 8 + hq];
        u1.i = h2i[(size_t)col[j + 2]  * 8 + hq];
        u2.i = h2i[(size_t)col[j + 4]  * 8 + hq];
        u3.i = h2i[(size_t)col[j + 6]  * 8 + hq];
        u4.i = h2i[(size_t)col[j + 8]  * 8 + hq];
        u5.i = h2i[(size_t)col[j + 10] * 8 + hq];
        u6.i = h2i[(size_t)col[j + 12] * 8 + hq];
        u7.i = h2i[(size_t)col[j + 14] * 8 + hq];
        acc = __hadd2(acc, u0.h); acc = __hadd2(acc, u1.h);
        acc = __hadd2(acc, u2.h); acc = __hadd2(acc, u3.h);
        acc = __hadd2(acc, u4.h); acc = __hadd2(acc, u5.h);
        acc = __hadd2(acc, u6.h); acc = __hadd2(acc, u7.h);
    }
    for (; j + 6 < end; j += 8) {
        H2 u0, u1, u2, u3;
        u0.i = h2i[(size_t)col[j]     * 8 + hq];
        u1.i = h2i[(size_t)col[j + 2] * 8 + hq];
        u2.i = h2i[(size_t)col[j + 4] * 8 + hq];
        u3.i = h2i[(size_t)col[j + 6] * 8 + hq];
        acc = __hadd2(acc, u0.h); acc = __hadd2(acc, u1.h);
        acc = __hadd2(acc, u2.h); acc = __hadd2(acc, u3.h);
    }
    for (; j < end; j += 2) {
        H2 u; u.i = h2i[(size_t)col[j] * 8 + hq];
        acc = __hadd2(acc, u.h);
    }
    acc = __hadd2(acc, shfl_xor_h2(acc, 8));
    // every lane now holds full p3 fragment for its hq (both eo copies identical)
    float dn = dis[n];
    int slot = (t0 & 63) & ~15;          // wave-lane base of this 16-lane slot
    H2 av; av.h = acc;
    float oA = 0.f, oB = 0.f, oC = 0.f;  // cols li, li+16, li+32
    #pragma unroll
    for (int hh = 0; hh < 8; ++hh) {
        H2 u; u.i = __shfl(av.i, slot + hh);
        float2 p = __half22float2(u.h);
        float p0 = dn * p.x, p1 = dn * p.y;
        int k0 = hh * 2;
        oA = fmaf(p0, sw[k0 * 40 + li],            oA);
        oA = fmaf(p1, sw[(k0 + 1) * 40 + li],      oA);
        oB = fmaf(p0, sw[k0 * 40 + li + 16],       oB);
        oB = fmaf(p1, sw[(k0 + 1) * 40 + li + 16], oB);
        if (li < 8) {
            oC = fmaf(p0, sw[k0 * 40 + li + 32],       oC);
            oC = fmaf(p1, sw[(k0 + 1) * 40 + li + 32], oC);
        }
    }
    float* orow = out + (size_t)n * 40;
    orow[li]      = oA + sb[li];
    orow[li + 16] = oB + sb[li + 16];
    if (li < 8) orow[li + 32] = oC + sb[li + 32];
}

// ---------------- launch ----------------

extern "C" void kernel_launch(void* const* d_in, const int* in_sizes, int n_in,
                              void* d_out, int out_size, void* d_ws, size_t ws_size,
                              hipStream_t stream) {
    const float* x  = (const float*)d_in[0];
    const int*   ei = (const int*)d_in[1];
    const float* W1 = (const float*)d_in[2];
    const float* b1 = (const float*)d_in[3];
    const float* W2 = (const float*)d_in[4];
    const float* b2 = (const float*)d_in[5];
    const float* W3 = (const float*)d_in[6];
    const float* b3 = (const float*)d_in[7];
    float* out = (float*)d_out;

    int N = in_sizes[0] / 256;   // 100000
    int E = in_sizes[1] / 2;     // 3200000
    const int* src = ei;
    const int* dst = ei + E;
    int NBUK = (N + BSZ - 1) >> BP;   // 1563

    char* w = (char*)d_ws;
    auto alloc = [&](size_t bytes) {
        char* p = w;
        w += (bytes + 255) & ~(size_t)255;
        return p;
    };
    int*    rowptr  = (int*)   alloc((size_t)(N + 1) * 4);
    int*    bhist   = (int*)   alloc((size_t)(NBUK + 1) * 4);  // +1: work-steal cursor
    int*    bbase   = (int*)   alloc((size_t)(NBUK + 1) * 4);
    int*    bcur    = (int*)   alloc((size_t)NBUK * 4);
    int*    ebuf    = (int*)   alloc((size_t)E * 4);
    int*    colx    = (int*)   alloc((size_t)(E + N) * 4);
    float*  dis     = (float*) alloc((size_t)N * 4);
    __half* W1t     = (__half*)alloc((size_t)128 * 256 * 2);
    __half* h1h     = (__half*)alloc((size_t)N * 128 * 2);
    __half* h2h     = (__half*)alloc((size_t)N * 16 * 2);
    __half* x2h     = (__half*)alloc((size_t)N * 16 * 2);
    int* wctr = bhist + NBUK;

    (void)hipMemsetAsync(bhist, 0, (size_t)(NBUK + 1) * 4, stream);
    kinit   <<<384, 256, 0, stream>>>(dst, bhist, E, NBUK, W1, W1t);
    bscan   <<<1, 1024, 0, stream>>>(bhist, bbase, bcur, NBUK);
    int SC_BLOCKS = 256;
    int chunk = (E + SC_BLOCKS - 1) / SC_BLOCKS;
    kscatter2<<<SC_BLOCKS, 256, 0, stream>>>(src, dst, bcur, ebuf, E, NBUK, chunk);
    kbuild  <<<NBUK, 256, 0, stream>>>(ebuf, bbase, rowptr, dis, colx, N);

    int gtiles = (N + 63) / 64;
    gemm1_mfma<<<gtiles, 256, 0, stream>>>(x, W1t, dis, h1h, N);
    int PBLK = 2048;                     // 8192 waves = full residency (8 blk/CU)
    prop128g2 <<<PBLK, 256, 0, stream>>>(h1h, rowptr, colx,
                                         dis, b1, W2, h2h, N, wctr);
    prop16    <<<(N * 16 + 255) / 256, 256, 0, stream>>>(h2h, rowptr, colx,
                                                         dis, b2, x2h, N);
    prop16_gemm3<<<(N * 16 + 255) / 256, 256, 0, stream>>>(x2h, rowptr, colx,
                                                           dis, W3, b3, out, N);
}

// Round 7
// 528.642 us; speedup vs baseline: 1.5571x; 1.5571x over previous
//
#include <hip/hip_runtime.h>
#include <hip/hip_fp16.h>
#include <math.h>

#define LEAKY 0.2f
#define BP 6                     // nodes per bucket = 64
#define BSZ 64
#define NBUK_MAX 2048

typedef _Float16 f16x8 __attribute__((ext_vector_type(8)));
typedef float f32x4 __attribute__((ext_vector_type(4)));

union H2 { __half2 h; int i; };
union H8 { __half2 h[4]; float4 f; };
union H4 { __half2 h[2]; float2 f; };

__device__ inline __half2 shfl_xor_h2(__half2 v, int m) {
    H2 u; u.h = v;
    u.i = __shfl_xor(u.i, m);
    return u.h;
}

// ---------------- kinit: khist (blocks 0..255) + W1 transpose (256..383) ----------------
__global__ __launch_bounds__(256) void kinit(const int* __restrict__ dst,
                                             int* __restrict__ bhist,
                                             int E, int nbuk,
                                             const float* __restrict__ W1,
                                             __half* __restrict__ W1t) {
    if (blockIdx.x < 256) {
        __shared__ int hist[NBUK_MAX];
        int t = threadIdx.x;
        for (int i = t; i < nbuk; i += 256) hist[i] = 0;
        __syncthreads();
        for (int e = blockIdx.x * 256 + t; e < E; e += 65536)
            atomicAdd(&hist[dst[e] >> BP], 1);
        __syncthreads();
        for (int i = t; i < nbuk; i += 256) {
            int v = hist[i];
            if (v) atomicAdd(&bhist[i], v);
        }
    } else {
        int idx = (blockIdx.x - 256) * 256 + threadIdx.x;
        if (idx < 32768) {
            int n = idx >> 8, k = idx & 255;              // W1t[128][256]
            W1t[idx] = __float2half(W1[k * 128 + n]);
        }
    }
}

// single-block exclusive scan of bucket counts -> bbase, bcur
__global__ __launch_bounds__(1024) void bscan(const int* __restrict__ bhist,
                                              int* __restrict__ bbase,
                                              int* __restrict__ bcur, int nbuk) {
    __shared__ int s[1024];
    int t = threadIdx.x;
    int v[4]; int sum = 0;
    #pragma unroll
    for (int i = 0; i < 4; ++i) {
        int idx = t * 4 + i;
        v[i] = (idx < nbuk) ? bhist[idx] : 0;
        sum += v[i];
    }
    s[t] = sum; __syncthreads();
    for (int off = 1; off < 1024; off <<= 1) {
        int a = (t >= off) ? s[t - off] : 0;
        __syncthreads();
        s[t] += a;
        __syncthreads();
    }
    int run = (t > 0) ? s[t - 1] : 0;
    #pragma unroll
    for (int i = 0; i < 4; ++i) {
        int idx = t * 4 + i;
        if (idx < nbuk) { bbase[idx] = run; bcur[idx] = run; run += v[i]; }
    }
    if (t == 1023) bbase[nbuk] = s[1023];
}

// block-local binning scatter
__global__ __launch_bounds__(256) void kscatter2(const int* __restrict__ src,
                                                 const int* __restrict__ dst,
                                                 int* __restrict__ bcur,
                                                 int* __restrict__ ebuf,
                                                 int E, int nbuk, int chunk) {
    __shared__ int hist[NBUK_MAX];
    int t = threadIdx.x;
    int base = blockIdx.x * chunk;
    int end = min(base + chunk, E);
    for (int i = t; i < nbuk; i += 256) hist[i] = 0;
    __syncthreads();
    for (int e = base + t; e < end; e += 256)
        atomicAdd(&hist[dst[e] >> BP], 1);
    __syncthreads();
    for (int i = t; i < nbuk; i += 256) {
        int c = hist[i];
        hist[i] = c ? atomicAdd(&bcur[i], c) : 0;
    }
    __syncthreads();
    for (int e = base + t; e < end; e += 256) {
        int d = dst[e];
        int pos = atomicAdd(&hist[d >> BP], 1);
        ebuf[pos] = ((d & (BSZ - 1)) << 17) | src[e];
    }
}

// merged count+scan+place: per-bucket counts -> rowptr + dis, then place into col.
// Second ebuf pass hits L1/L2 (avg bucket = 8 KB).
__global__ __launch_bounds__(256) void kbuild(const int* __restrict__ ebuf,
                                              const int* __restrict__ bbase,
                                              int* __restrict__ rowptr,
                                              float* __restrict__ dis,
                                              int* __restrict__ col, int N) {
    __shared__ int h[BSZ];
    __shared__ int cur[BSZ];
    int b = blockIdx.x, t = threadIdx.x;
    if (t < BSZ) h[t] = 0;
    __syncthreads();
    int beg = bbase[b], end = bbase[b + 1];
    for (int j = beg + t; j < end; j += 256)
        atomicAdd(&h[(ebuf[j] >> 17) & (BSZ - 1)], 1);
    __syncthreads();
    if (t < BSZ) {                      // threads 0..63 = wave 0
        int node = b * BSZ + t;
        int c = (node < N) ? h[t] + 1 : 0;   // +1 self-loop
        int incl = c;
        #pragma unroll
        for (int off = 1; off < 64; off <<= 1) {
            int v = __shfl_up(incl, off);
            if (t >= off) incl += v;
        }
        int colbase = beg + b * BSZ;
        if (node < N) {
            int r = colbase + incl - c;
            rowptr[node] = r;
            dis[node] = rsqrtf((float)c);
            col[r] = node;              // self-loop first
            cur[t] = r + 1;
            if (node == N - 1) rowptr[N] = colbase + incl;
        }
    }
    __syncthreads();
    for (int j = beg + t; j < end; j += 256) {
        int v = ebuf[j];
        int p = atomicAdd(&cur[(v >> 17) & (BSZ - 1)], 1);
        col[p] = v & 0x1FFFF;
    }
}

// ---------------- GEMM1: [M,256]fp32 @ W1t[128,256]fp16 -> fp16, *= dis[row] ----------------
__global__ __launch_bounds__(256) void gemm1_mfma(
        const float* __restrict__ x, const __half* __restrict__ W1t,
        const float* __restrict__ dis, __half* __restrict__ C, int M) {
    int wave = threadIdx.x >> 6;
    int lane = threadIdx.x & 63;
    int m = lane & 15, q = lane >> 4;
    int row0 = (blockIdx.x * 4 + wave) * 16;
    int arow = row0 + m;
    bool aval = arow < M;
    const float* xr = x + (size_t)arow * 256 + q * 8;
    f32x4 acc[8];
    #pragma unroll
    for (int c = 0; c < 8; ++c) acc[c] = (f32x4){0.f, 0.f, 0.f, 0.f};
    for (int k0 = 0; k0 < 256; k0 += 32) {
        f16x8 a;
        if (aval) {
            float4 v0 = *(const float4*)(xr + k0);
            float4 v1 = *(const float4*)(xr + k0 + 4);
            a[0] = (_Float16)v0.x; a[1] = (_Float16)v0.y;
            a[2] = (_Float16)v0.z; a[3] = (_Float16)v0.w;
            a[4] = (_Float16)v1.x; a[5] = (_Float16)v1.y;
            a[6] = (_Float16)v1.z; a[7] = (_Float16)v1.w;
        } else {
            #pragma unroll
            for (int i = 0; i < 8; ++i) a[i] = (_Float16)0.f;
        }
        #pragma unroll
        for (int c = 0; c < 8; ++c) {
            f16x8 b = *(const f16x8*)(W1t + (size_t)(c * 16 + m) * 256 + k0 + q * 8);
            acc[c] = __builtin_amdgcn_mfma_f32_16x16x32_f16(a, b, acc[c], 0, 0, 0);
        }
    }
    float dw[4];
    #pragma unroll
    for (int r = 0; r < 4; ++r) {
        int rr = row0 + q * 4 + r;
        dw[r] = (rr < M) ? dis[rr] : 0.f;
    }
    #pragma unroll
    for (int c = 0; c < 8; ++c) {
        #pragma unroll
        for (int r = 0; r < 4; ++r) {
            int rr = row0 + q * 4 + r;
            if (rr < M)
                C[(size_t)rr * 128 + c * 16 + m] = __float2half(acc[c][r] * dw[r]);
        }
    }
}

// ---------------- prop128g2: aggregate h1 (128 fp16) + fused layer-2 GEMM epilogue ----------------
// out = h2h[n][16] = dis[n] * ( leaky(dis[n]*sum + b1) @ W2 )
// W2 staged in LDS, layout sw[f*256 + eo*64 + q*4 + j] = W2[(q*8+f)*16 + eo*4 + j].
// Staging writes are LINEAR (conflict-free); permutation applied to the global
// source index (W2 is 8 KB, L1-resident -> scattered reads cheap).
__global__ __launch_bounds__(256) void prop128g2(
        const __half* __restrict__ h, const int* __restrict__ rowptr,
        const int* __restrict__ col, const float* __restrict__ dis,
        const float* __restrict__ bias, const float* __restrict__ W2,
        __half* __restrict__ out, int N) {
    __shared__ float sw[2048];              // 8 KB, exact
    for (int k = threadIdx.x; k < 2048; k += 256) {
        int f  = k >> 8;                    // 0..7
        int r  = k & 255;
        int e2 = r >> 6;                    // 0..3
        int qq = (r >> 2) & 15;             // 0..15
        int jj = r & 3;
        sw[k] = W2[(qq * 8 + f) * 16 + e2 * 4 + jj];
    }
    __syncthreads();

    int n = (blockIdx.x * 256 + threadIdx.x) >> 6;
    if (n >= N) return;
    int lane = threadIdx.x & 63;
    int eo = lane >> 4;
    int q = lane & 15;
    const float4* __restrict__ h4 = (const float4*)h;
    int beg = rowptr[n], end = rowptr[n + 1];
    __half2 acc[4];
    acc[0] = acc[1] = acc[2] = acc[3] = __float2half2_rn(0.f);
    int j = beg + eo;
    for (; j + 28 < end; j += 32) {     // 32 edges in flight per wave
        int s0 = col[j],      s1 = col[j + 4],  s2 = col[j + 8],  s3 = col[j + 12];
        int s4 = col[j + 16], s5 = col[j + 20], s6 = col[j + 24], s7 = col[j + 28];
        H8 u0, u1, u2, u3, u4, u5, u6, u7;
        u0.f = h4[(size_t)s0 * 16 + q];
        u1.f = h4[(size_t)s1 * 16 + q];
        u2.f = h4[(size_t)s2 * 16 + q];
        u3.f = h4[(size_t)s3 * 16 + q];
        u4.f = h4[(size_t)s4 * 16 + q];
        u5.f = h4[(size_t)s5 * 16 + q];
        u6.f = h4[(size_t)s6 * 16 + q];
        u7.f = h4[(size_t)s7 * 16 + q];
        #pragma unroll
        for (int i = 0; i < 4; ++i) acc[i] = __hadd2(acc[i], u0.h[i]);
        #pragma unroll
        for (int i = 0; i < 4; ++i) acc[i] = __hadd2(acc[i], u1.h[i]);
        #pragma unroll
        for (int i = 0; i < 4; ++i) acc[i] = __hadd2(acc[i], u2.h[i]);
        #pragma unroll
        for (int i = 0; i < 4; ++i) acc[i] = __hadd2(acc[i], u3.h[i]);
        #pragma unroll
        for (int i = 0; i < 4; ++i) acc[i] = __hadd2(acc[i], u4.h[i]);
        #pragma unroll
        for (int i = 0; i < 4; ++i) acc[i] = __hadd2(acc[i], u5.h[i]);
        #pragma unroll
        for (int i = 0; i < 4; ++i) acc[i] = __hadd2(acc[i], u6.h[i]);
        #pragma unroll
        for (int i = 0; i < 4; ++i) acc[i] = __hadd2(acc[i], u7.h[i]);
    }
    for (; j + 12 < end; j += 16) {
        int s0 = col[j], s1 = col[j + 4], s2 = col[j + 8], s3 = col[j + 12];
        H8 u0, u1, u2, u3;
        u0.f = h4[(size_t)s0 * 16 + q];
        u1.f = h4[(size_t)s1 * 16 + q];
        u2.f = h4[(size_t)s2 * 16 + q];
        u3.f = h4[(size_t)s3 * 16 + q];
        #pragma unroll
        for (int i = 0; i < 4; ++i) acc[i] = __hadd2(acc[i], u0.h[i]);
        #pragma unroll
        for (int i = 0; i < 4; ++i) acc[i] = __hadd2(acc[i], u1.h[i]);
        #pragma unroll
        for (int i = 0; i < 4; ++i) acc[i] = __hadd2(acc[i], u2.h[i]);
        #pragma unroll
        for (int i = 0; i < 4; ++i) acc[i] = __hadd2(acc[i], u3.h[i]);
    }
    for (; j + 4 < end; j += 8) {
        int s0 = col[j], s1 = col[j + 4];
        H8 u0, u1;
        u0.f = h4[(size_t)s0 * 16 + q];
        u1.f = h4[(size_t)s1 * 16 + q];
        #pragma unroll
        for (int i = 0; i < 4; ++i) acc[i] = __hadd2(acc[i], u0.h[i]);
        #pragma unroll
        for (int i = 0; i < 4; ++i) acc[i] = __hadd2(acc[i], u1.h[i]);
    }
    for (; j < end; j += 4) {
        int s = col[j];
        H8 u; u.f = h4[(size_t)s * 16 + q];
        #pragma unroll
        for (int i = 0; i < 4; ++i) acc[i] = __hadd2(acc[i], u.h[i]);
    }
    #pragma unroll
    for (int i = 0; i < 4; ++i) {
        acc[i] = __hadd2(acc[i], shfl_xor_h2(acc[i], 16));
        acc[i] = __hadd2(acc[i], shfl_xor_h2(acc[i], 32));
    }
    // --- fused epilogue: x1 row fragment (8 feats q*8..q*8+7) in every lane -> @W2 ---
    float dn = dis[n];
    const float4* b4 = (const float4*)bias;
    float4 bA = b4[q * 2];
    float4 bB = b4[q * 2 + 1];
    float2 f0 = __half22float2(acc[0]);
    float2 f1 = __half22float2(acc[1]);
    float2 f2 = __half22float2(acc[2]);
    float2 f3 = __half22float2(acc[3]);
    float xf[8];
    xf[0] = fmaf(dn, f0.x, bA.x); xf[1] = fmaf(dn, f0.y, bA.y);
    xf[2] = fmaf(dn, f1.x, bA.z); xf[3] = fmaf(dn, f1.y, bA.w);
    xf[4] = fmaf(dn, f2.x, bB.x); xf[5] = fmaf(dn, f2.y, bB.y);
    xf[6] = fmaf(dn, f3.x, bB.z); xf[7] = fmaf(dn, f3.y, bB.w);
    #pragma unroll
    for (int i = 0; i < 8; ++i) xf[i] = xf[i] > 0.f ? xf[i] : LEAKY * xf[i];
    // lane (eo,q) computes h2 cols [eo*4, eo*4+4) over features [q*8, q*8+8)
    float p0 = 0.f, p1 = 0.f, p2 = 0.f, p3 = 0.f;
    #pragma unroll
    for (int f = 0; f < 8; ++f) {
        f32x4 wv = *(const f32x4*)&sw[f * 256 + eo * 64 + q * 4];
        p0 = fmaf(xf[f], wv[0], p0);
        p1 = fmaf(xf[f], wv[1], p1);
        p2 = fmaf(xf[f], wv[2], p2);
        p3 = fmaf(xf[f], wv[3], p3);
    }
    #pragma unroll
    for (int mm = 1; mm < 16; mm <<= 1) {   // reduce over 16 q-lanes
        p0 += __shfl_xor(p0, mm);
        p1 += __shfl_xor(p1, mm);
        p2 += __shfl_xor(p2, mm);
        p3 += __shfl_xor(p3, mm);
    }
    if (q == 0) {
        H4 w;
        w.h[0] = __floats2half2_rn(p0 * dn, p1 * dn);
        w.h[1] = __floats2half2_rn(p2 * dn, p3 * dn);
        ((float2*)out)[(size_t)n * 4 + eo] = w.f;
    }
}

// ---------------- prop16: 16 lanes/node, 2 slots x 8 lanes, 16 edges in flight ----------------
// h rows fp16 pre-scaled by dis[src]; output x2 = dis*leaky(dis*sum + b) (pre-scaled fp16)
__global__ __launch_bounds__(256) void prop16(
        const __half* __restrict__ h, const int* __restrict__ rowptr,
        const int* __restrict__ col, const float* __restrict__ dis,
        const float* __restrict__ bias, __half* __restrict__ outp, int N) {
    int t = blockIdx.x * 256 + threadIdx.x;
    int n = t >> 4;
    if (n >= N) return;
    int li = threadIdx.x & 15;
    int eo = li >> 3;
    int hq = li & 7;
    const int* __restrict__ h2i = (const int*)h;
    int beg = rowptr[n], end = rowptr[n + 1];
    __half2 acc = __float2half2_rn(0.f);
    int j = beg + eo;
    for (; j + 14 < end; j += 16) {     // 16 edges in flight per node
        H2 u0, u1, u2, u3, u4, u5, u6, u7;
        u0.i = h2i[(size_t)col[j]      * 8 + hq];
        u1.i = h2i[(size_t)col[j + 2]  * 8 + hq];
        u2.i = h2i[(size_t)col[j + 4]  * 8 + hq];
        u3.i = h2i[(size_t)col[j + 6]  * 8 + hq];
        u4.i = h2i[(size_t)col[j + 8]  * 8 + hq];
        u5.i = h2i[(size_t)col[j + 10] * 8 + hq];
        u6.i = h2i[(size_t)col[j + 12] * 8 + hq];
        u7.i = h2i[(size_t)col[j + 14] * 8 + hq];
        acc = __hadd2(acc, u0.h); acc = __hadd2(acc, u1.h);
        acc = __hadd2(acc, u2.h); acc = __hadd2(acc, u3.h);
        acc = __hadd2(acc, u4.h); acc = __hadd2(acc, u5.h);
        acc = __hadd2(acc, u6.h); acc = __hadd2(acc, u7.h);
    }
    for (; j + 6 < end; j += 8) {
        H2 u0, u1, u2, u3;
        u0.i = h2i[(size_t)col[j]     * 8 + hq];
        u1.i = h2i[(size_t)col[j + 2] * 8 + hq];
        u2.i = h2i[(size_t)col[j + 4] * 8 + hq];
        u3.i = h2i[(size_t)col[j + 6] * 8 + hq];
        acc = __hadd2(acc, u0.h); acc = __hadd2(acc, u1.h);
        acc = __hadd2(acc, u2.h); acc = __hadd2(acc, u3.h);
    }
    for (; j < end; j += 2) {
        H2 u; u.i = h2i[(size_t)col[j] * 8 + hq];
        acc = __hadd2(acc, u.h);
    }
    acc = __hadd2(acc, shfl_xor_h2(acc, 8));
    if (eo == 0) {
        float dn = dis[n];
        float2 f = __half22float2(acc);
        float ox = fmaf(dn, f.x, bias[hq * 2]);
        float oy = fmaf(dn, f.y, bias[hq * 2 + 1]);
        ox = ox > 0.f ? ox : LEAKY * ox;
        oy = oy > 0.f ? oy : LEAKY * oy;
        ox *= dn; oy *= dn;
        H2 w; w.h = __floats2half2_rn(ox, oy);
        ((int*)outp)[(size_t)n * 8 + hq] = w.i;
    }
}

// ---------------- prop16_gemm3: gather x2 -> p3 (registers) -> @W3 + b3 -> out ----------------
__global__ __launch_bounds__(256) void prop16_gemm3(
        const __half* __restrict__ h, const int* __restrict__ rowptr,
        const int* __restrict__ col, const float* __restrict__ dis,
        const float* __restrict__ W3, const float* __restrict__ b3,
        float* __restrict__ out, int N) {
    __shared__ float sw[640];
    __shared__ float sb[40];
    int t0 = threadIdx.x;
    for (int i = t0; i < 640; i += 256) sw[i] = W3[i];
    if (t0 < 40) sb[t0] = b3[t0];
    __syncthreads();
    int t = blockIdx.x * 256 + t0;
    int n = t >> 4;
    if (n >= N) return;
    int li = t0 & 15;
    int eo = li >> 3;
    int hq = li & 7;
    const int* __restrict__ h2i = (const int*)h;
    int beg = rowptr[n], end = rowptr[n + 1];
    __half2 acc = __float2half2_rn(0.f);
    int j = beg + eo;
    for (; j + 14 < end; j += 16) {
        H2 u0, u1, u2, u3, u4, u5, u6, u7;
        u0.i = h2i[(size_t)col[j]      * 8 + hq];
        u1.i = h2i[(size_t)col[j + 2]  * 8 + hq];
        u2.i = h2i[(size_t)col[j + 4]  * 8 + hq];
        u3.i = h2i[(size_t)col[j + 6]  * 8 + hq];
        u4.i = h2i[(size_t)col[j + 8]  * 8 + hq];
        u5.i = h2i[(size_t)col[j + 10] * 8 + hq];
        u6.i = h2i[(size_t)col[j + 12] * 8 + hq];
        u7.i = h2i[(size_t)col[j + 14] * 8 + hq];
        acc = __hadd2(acc, u0.h); acc = __hadd2(acc, u1.h);
        acc = __hadd2(acc, u2.h); acc = __hadd2(acc, u3.h);
        acc = __hadd2(acc, u4.h); acc = __hadd2(acc, u5.h);
        acc = __hadd2(acc, u6.h); acc = __hadd2(acc, u7.h);
    }
    for (; j + 6 < end; j += 8) {
        H2 u0, u1, u2, u3;
        u0.i = h2i[(size_t)col[j]     * 8 + hq];
        u1.i = h2i[(size_t)col[j + 2] * 8 + hq];
        u2.i = h2i[(size_t)col[j + 4] * 8 + hq];
        u3.i = h2i[(size_t)col[j + 6] * 8 + hq];
        acc = __hadd2(acc, u0.h); acc = __hadd2(acc, u1.h);
        acc = __hadd2(acc, u2.h); acc = __hadd2(acc, u3.h);
    }
    for (; j < end; j += 2) {
        H2 u; u.i = h2i[(size_t)col[j] * 8 + hq];
        acc = __hadd2(acc, u.h);
    }
    acc = __hadd2(acc, shfl_xor_h2(acc, 8));
    // every lane now holds full p3 fragment for its hq (both eo copies identical)
    float dn = dis[n];
    int slot = (t0 & 63) & ~15;          // wave-lane base of this 16-lane slot
    H2 av; av.h = acc;
    float oA = 0.f, oB = 0.f, oC = 0.f;  // cols li, li+16, li+32
    #pragma unroll
    for (int hh = 0; hh < 8; ++hh) {
        H2 u; u.i = __shfl(av.i, slot + hh);
        float2 p = __half22float2(u.h);
        float p0 = dn * p.x, p1 = dn * p.y;
        int k0 = hh * 2;
        oA = fmaf(p0, sw[k0 * 40 + li],            oA);
        oA = fmaf(p1, sw[(k0 + 1) * 40 + li],      oA);
        oB = fmaf(p0, sw[k0 * 40 + li + 16],       oB);
        oB = fmaf(p1, sw[(k0 + 1) * 40 + li + 16], oB);
        if (li < 8) {
            oC = fmaf(p0, sw[k0 * 40 + li + 32],       oC);
            oC = fmaf(p1, sw[(k0 + 1) * 40 + li + 32], oC);
        }
    }
    float* orow = out + (size_t)n * 40;
    orow[li]      = oA + sb[li];
    orow[li + 16] = oB + sb[li + 16];
    if (li < 8) orow[li + 32] = oC + sb[li + 32];
}

// ---------------- launch ----------------

extern "C" void kernel_launch(void* const* d_in, const int* in_sizes, int n_in,
                              void* d_out, int out_size, void* d_ws, size_t ws_size,
                              hipStream_t stream) {
    const float* x  = (const float*)d_in[0];
    const int*   ei = (const int*)d_in[1];
    const float* W1 = (const float*)d_in[2];
    const float* b1 = (const float*)d_in[3];
    const float* W2 = (const float*)d_in[4];
    const float* b2 = (const float*)d_in[5];
    const float* W3 = (const float*)d_in[6];
    const float* b3 = (const float*)d_in[7];
    float* out = (float*)d_out;

    int N = in_sizes[0] / 256;   // 100000
    int E = in_sizes[1] / 2;     // 3200000
    const int* src = ei;
    const int* dst = ei + E;
    int NBUK = (N + BSZ - 1) >> BP;   // 1563

    char* w = (char*)d_ws;
    auto alloc = [&](size_t bytes) {
        char* p = w;
        w += (bytes + 255) & ~(size_t)255;
        return p;
    };
    int*    rowptr  = (int*)   alloc((size_t)(N + 1) * 4);
    int*    bhist   = (int*)   alloc((size_t)NBUK * 4);
    int*    bbase   = (int*)   alloc((size_t)(NBUK + 1) * 4);
    int*    bcur    = (int*)   alloc((size_t)NBUK * 4);
    int*    ebuf    = (int*)   alloc((size_t)E * 4);
    int*    colx    = (int*)   alloc((size_t)(E + N) * 4);
    float*  dis     = (float*) alloc((size_t)N * 4);
    __half* W1t     = (__half*)alloc((size_t)128 * 256 * 2);
    __half* h1h     = (__half*)alloc((size_t)N * 128 * 2);
    __half* h2h     = (__half*)alloc((size_t)N * 16 * 2);
    __half* x2h     = (__half*)alloc((size_t)N * 16 * 2);

    (void)hipMemsetAsync(bhist, 0, (size_t)NBUK * 4, stream);
    kinit   <<<384, 256, 0, stream>>>(dst, bhist, E, NBUK, W1, W1t);
    bscan   <<<1, 1024, 0, stream>>>(bhist, bbase, bcur, NBUK);
    int SC_BLOCKS = 256;
    int chunk = (E + SC_BLOCKS - 1) / SC_BLOCKS;
    kscatter2<<<SC_BLOCKS, 256, 0, stream>>>(src, dst, bcur, ebuf, E, NBUK, chunk);
    kbuild  <<<NBUK, 256, 0, stream>>>(ebuf, bbase, rowptr, dis, colx, N);

    int gtiles = (N + 63) / 64;
    gemm1_mfma<<<gtiles, 256, 0, stream>>>(x, W1t, dis, h1h, N);
    prop128g2 <<<(N * 64 + 255) / 256, 256, 0, stream>>>(h1h, rowptr, colx,
                                                         dis, b1, W2, h2h, N);
    prop16    <<<(N * 16 + 255) / 256, 256, 0, stream>>>(h2h, rowptr, colx,
                                                         dis, b2, x2h, N);
    prop16_gemm3<<<(N * 16 + 255) / 256, 256, 0, stream>>>(x2h, rowptr, colx,
                                                           dis, W3, b3, out, N);
}

// Round 8
// 523.601 us; speedup vs baseline: 1.5721x; 1.0096x over previous
//
#include <hip/hip_runtime.h>
#include <hip/hip_fp16.h>
#include <math.h>

#define LEAKY 0.2f
#define BP 6                     // nodes per bucket = 64
#define BSZ 64
#define NBUK_MAX 2048

typedef _Float16 f16x8 __attribute__((ext_vector_type(8)));
typedef float f32x4 __attribute__((ext_vector_type(4)));

union H2 { __half2 h; int i; };
union H8 { __half2 h[4]; float4 f; };
union H4 { __half2 h[2]; float2 f; };

__device__ inline __half2 shfl_xor_h2(__half2 v, int m) {
    H2 u; u.h = v;
    u.i = __shfl_xor(u.i, m);
    return u.h;
}

// ---------------- kinit: chunked khist (blocks 0..255, persists per-block hist)
// ----------------        + W1 transpose (256..383) ----------------
__global__ __launch_bounds__(256) void kinit(const int* __restrict__ dst,
                                             int* __restrict__ bhist,
                                             int* __restrict__ bhB,
                                             int E, int nbuk, int chunk,
                                             const float* __restrict__ W1,
                                             __half* __restrict__ W1t) {
    if (blockIdx.x < 256) {
        __shared__ int hist[NBUK_MAX];
        int t = threadIdx.x;
        for (int i = t; i < nbuk; i += 256) hist[i] = 0;
        __syncthreads();
        int base = blockIdx.x * chunk;
        int end = min(base + chunk, E);
        for (int e = base + t; e < end; e += 256)
            atomicAdd(&hist[dst[e] >> BP], 1);
        __syncthreads();
        int* myrow = bhB + (size_t)blockIdx.x * nbuk;
        for (int i = t; i < nbuk; i += 256) {
            int v = hist[i];
            myrow[i] = v;                       // persist for kscatter2
            if (v) atomicAdd(&bhist[i], v);
        }
    } else {
        int idx = (blockIdx.x - 256) * 256 + threadIdx.x;
        if (idx < 32768) {
            int n = idx >> 8, k = idx & 255;              // W1t[128][256]
            W1t[idx] = __float2half(W1[k * 128 + n]);
        }
    }
}

// single-block exclusive scan of bucket counts -> bbase, bcur
__global__ __launch_bounds__(1024) void bscan(const int* __restrict__ bhist,
                                              int* __restrict__ bbase,
                                              int* __restrict__ bcur, int nbuk) {
    __shared__ int s[1024];
    int t = threadIdx.x;
    int v[4]; int sum = 0;
    #pragma unroll
    for (int i = 0; i < 4; ++i) {
        int idx = t * 4 + i;
        v[i] = (idx < nbuk) ? bhist[idx] : 0;
        sum += v[i];
    }
    s[t] = sum; __syncthreads();
    for (int off = 1; off < 1024; off <<= 1) {
        int a = (t >= off) ? s[t - off] : 0;
        __syncthreads();
        s[t] += a;
        __syncthreads();
    }
    int run = (t > 0) ? s[t - 1] : 0;
    #pragma unroll
    for (int i = 0; i < 4; ++i) {
        int idx = t * 4 + i;
        if (idx < nbuk) { bbase[idx] = run; bcur[idx] = run; run += v[i]; }
    }
    if (t == 1023) bbase[nbuk] = s[1023];
}

// binning scatter: per-block hist precomputed by kinit (no recount pass)
__global__ __launch_bounds__(256) void kscatter2(const int* __restrict__ src,
                                                 const int* __restrict__ dst,
                                                 int* __restrict__ bcur,
                                                 const int* __restrict__ bhB,
                                                 int* __restrict__ ebuf,
                                                 int E, int nbuk, int chunk) {
    __shared__ int hist[NBUK_MAX];
    int t = threadIdx.x;
    int base = blockIdx.x * chunk;
    int end = min(base + chunk, E);
    const int* myrow = bhB + (size_t)blockIdx.x * nbuk;
    for (int i = t; i < nbuk; i += 256) {
        int c = myrow[i];
        hist[i] = c ? atomicAdd(&bcur[i], c) : 0;
    }
    __syncthreads();
    for (int e = base + t; e < end; e += 256) {
        int d = dst[e];
        int pos = atomicAdd(&hist[d >> BP], 1);
        ebuf[pos] = ((d & (BSZ - 1)) << 17) | src[e];
    }
}

// merged count+scan+place: per-bucket counts -> rowptr + dis, then place into col.
// Second ebuf pass hits L1/L2 (avg bucket = 8 KB).
__global__ __launch_bounds__(256) void kbuild(const int* __restrict__ ebuf,
                                              const int* __restrict__ bbase,
                                              int* __restrict__ rowptr,
                                              float* __restrict__ dis,
                                              int* __restrict__ col, int N) {
    __shared__ int h[BSZ];
    __shared__ int cur[BSZ];
    int b = blockIdx.x, t = threadIdx.x;
    if (t < BSZ) h[t] = 0;
    __syncthreads();
    int beg = bbase[b], end = bbase[b + 1];
    for (int j = beg + t; j < end; j += 256)
        atomicAdd(&h[(ebuf[j] >> 17) & (BSZ - 1)], 1);
    __syncthreads();
    if (t < BSZ) {                      // threads 0..63 = wave 0
        int node = b * BSZ + t;
        int c = (node < N) ? h[t] + 1 : 0;   // +1 self-loop
        int incl = c;
        #pragma unroll
        for (int off = 1; off < 64; off <<= 1) {
            int v = __shfl_up(incl, off);
            if (t >= off) incl += v;
        }
        int colbase = beg + b * BSZ;
        if (node < N) {
            int r = colbase + incl - c;
            rowptr[node] = r;
            dis[node] = rsqrtf((float)c);
            col[r] = node;              // self-loop first
            cur[t] = r + 1;
            if (node == N - 1) rowptr[N] = colbase + incl;
        }
    }
    __syncthreads();
    for (int j = beg + t; j < end; j += 256) {
        int v = ebuf[j];
        int p = atomicAdd(&cur[(v >> 17) & (BSZ - 1)], 1);
        col[p] = v & 0x1FFFF;
    }
}

// ---------------- GEMM1: [M,256]fp32 @ W1t[128,256]fp16 -> fp16, *= dis[row] ----------------
__global__ __launch_bounds__(256) void gemm1_mfma(
        const float* __restrict__ x, const __half* __restrict__ W1t,
        const float* __restrict__ dis, __half* __restrict__ C, int M) {
    int wave = threadIdx.x >> 6;
    int lane = threadIdx.x & 63;
    int m = lane & 15, q = lane >> 4;
    int row0 = (blockIdx.x * 4 + wave) * 16;
    int arow = row0 + m;
    bool aval = arow < M;
    const float* xr = x + (size_t)arow * 256 + q * 8;
    f32x4 acc[8];
    #pragma unroll
    for (int c = 0; c < 8; ++c) acc[c] = (f32x4){0.f, 0.f, 0.f, 0.f};
    for (int k0 = 0; k0 < 256; k0 += 32) {
        f16x8 a;
        if (aval) {
            float4 v0 = *(const float4*)(xr + k0);
            float4 v1 = *(const float4*)(xr + k0 + 4);
            a[0] = (_Float16)v0.x; a[1] = (_Float16)v0.y;
            a[2] = (_Float16)v0.z; a[3] = (_Float16)v0.w;
            a[4] = (_Float16)v1.x; a[5] = (_Float16)v1.y;
            a[6] = (_Float16)v1.z; a[7] = (_Float16)v1.w;
        } else {
            #pragma unroll
            for (int i = 0; i < 8; ++i) a[i] = (_Float16)0.f;
        }
        #pragma unroll
        for (int c = 0; c < 8; ++c) {
            f16x8 b = *(const f16x8*)(W1t + (size_t)(c * 16 + m) * 256 + k0 + q * 8);
            acc[c] = __builtin_amdgcn_mfma_f32_16x16x32_f16(a, b, acc[c], 0, 0, 0);
        }
    }
    float dw[4];
    #pragma unroll
    for (int r = 0; r < 4; ++r) {
        int rr = row0 + q * 4 + r;
        dw[r] = (rr < M) ? dis[rr] : 0.f;
    }
    #pragma unroll
    for (int c = 0; c < 8; ++c) {
        #pragma unroll
        for (int r = 0; r < 4; ++r) {
            int rr = row0 + q * 4 + r;
            if (rr < M)
                C[(size_t)rr * 128 + c * 16 + m] = __float2half(acc[c][r] * dw[r]);
        }
    }
}

// ---------------- prop128g2: aggregate h1 (128 fp16) + fused layer-2 GEMM epilogue ----------------
// out = h2h[n][16] = dis[n] * ( leaky(dis[n]*sum + b1) @ W2 )
// W2 staged in LDS, layout sw[f*256 + eo*64 + q*4 + j] = W2[(q*8+f)*16 + eo*4 + j].
// Staging writes are LINEAR (conflict-free); permutation applied to the global
// source index (W2 is 8 KB, L1-resident -> scattered reads cheap).
__global__ __launch_bounds__(256) void prop128g2(
        const __half* __restrict__ h, const int* __restrict__ rowptr,
        const int* __restrict__ col, const float* __restrict__ dis,
        const float* __restrict__ bias, const float* __restrict__ W2,
        __half* __restrict__ out, int N) {
    __shared__ float sw[2048];              // 8 KB, exact
    for (int k = threadIdx.x; k < 2048; k += 256) {
        int f  = k >> 8;                    // 0..7
        int r  = k & 255;
        int e2 = r >> 6;                    // 0..3
        int qq = (r >> 2) & 15;             // 0..15
        int jj = r & 3;
        sw[k] = W2[(qq * 8 + f) * 16 + e2 * 4 + jj];
    }
    __syncthreads();

    int n = (blockIdx.x * 256 + threadIdx.x) >> 6;
    if (n >= N) return;
    int lane = threadIdx.x & 63;
    int eo = lane >> 4;
    int q = lane & 15;
    const float4* __restrict__ h4 = (const float4*)h;
    int beg = rowptr[n], end = rowptr[n + 1];
    __half2 acc[4];
    acc[0] = acc[1] = acc[2] = acc[3] = __float2half2_rn(0.f);
    int j = beg + eo;
    for (; j + 28 < end; j += 32) {     // 32 edges in flight per wave
        int s0 = col[j],      s1 = col[j + 4],  s2 = col[j + 8],  s3 = col[j + 12];
        int s4 = col[j + 16], s5 = col[j + 20], s6 = col[j + 24], s7 = col[j + 28];
        H8 u0, u1, u2, u3, u4, u5, u6, u7;
        u0.f = h4[(size_t)s0 * 16 + q];
        u1.f = h4[(size_t)s1 * 16 + q];
        u2.f = h4[(size_t)s2 * 16 + q];
        u3.f = h4[(size_t)s3 * 16 + q];
        u4.f = h4[(size_t)s4 * 16 + q];
        u5.f = h4[(size_t)s5 * 16 + q];
        u6.f = h4[(size_t)s6 * 16 + q];
        u7.f = h4[(size_t)s7 * 16 + q];
        #pragma unroll
        for (int i = 0; i < 4; ++i) acc[i] = __hadd2(acc[i], u0.h[i]);
        #pragma unroll
        for (int i = 0; i < 4; ++i) acc[i] = __hadd2(acc[i], u1.h[i]);
        #pragma unroll
        for (int i = 0; i < 4; ++i) acc[i] = __hadd2(acc[i], u2.h[i]);
        #pragma unroll
        for (int i = 0; i < 4; ++i) acc[i] = __hadd2(acc[i], u3.h[i]);
        #pragma unroll
        for (int i = 0; i < 4; ++i) acc[i] = __hadd2(acc[i], u4.h[i]);
        #pragma unroll
        for (int i = 0; i < 4; ++i) acc[i] = __hadd2(acc[i], u5.h[i]);
        #pragma unroll
        for (int i = 0; i < 4; ++i) acc[i] = __hadd2(acc[i], u6.h[i]);
        #pragma unroll
        for (int i = 0; i < 4; ++i) acc[i] = __hadd2(acc[i], u7.h[i]);
    }
    for (; j + 12 < end; j += 16) {
        int s0 = col[j], s1 = col[j + 4], s2 = col[j + 8], s3 = col[j + 12];
        H8 u0, u1, u2, u3;
        u0.f = h4[(size_t)s0 * 16 + q];
        u1.f = h4[(size_t)s1 * 16 + q];
        u2.f = h4[(size_t)s2 * 16 + q];
        u3.f = h4[(size_t)s3 * 16 + q];
        #pragma unroll
        for (int i = 0; i < 4; ++i) acc[i] = __hadd2(acc[i], u0.h[i]);
        #pragma unroll
        for (int i = 0; i < 4; ++i) acc[i] = __hadd2(acc[i], u1.h[i]);
        #pragma unroll
        for (int i = 0; i < 4; ++i) acc[i] = __hadd2(acc[i], u2.h[i]);
        #pragma unroll
        for (int i = 0; i < 4; ++i) acc[i] = __hadd2(acc[i], u3.h[i]);
    }
    for (; j + 4 < end; j += 8) {
        int s0 = col[j], s1 = col[j + 4];
        H8 u0, u1;
        u0.f = h4[(size_t)s0 * 16 + q];
        u1.f = h4[(size_t)s1 * 16 + q];
        #pragma unroll
        for (int i = 0; i < 4; ++i) acc[i] = __hadd2(acc[i], u0.h[i]);
        #pragma unroll
        for (int i = 0; i < 4; ++i) acc[i] = __hadd2(acc[i], u1.h[i]);
    }
    for (; j < end; j += 4) {
        int s = col[j];
        H8 u; u.f = h4[(size_t)s * 16 + q];
        #pragma unroll
        for (int i = 0; i < 4; ++i) acc[i] = __hadd2(acc[i], u.h[i]);
    }
    #pragma unroll
    for (int i = 0; i < 4; ++i) {
        acc[i] = __hadd2(acc[i], shfl_xor_h2(acc[i], 16));
        acc[i] = __hadd2(acc[i], shfl_xor_h2(acc[i], 32));
    }
    // --- fused epilogue: x1 row fragment (8 feats q*8..q*8+7) in every lane -> @W2 ---
    float dn = dis[n];
    const float4* b4 = (const float4*)bias;
    float4 bA = b4[q * 2];
    float4 bB = b4[q * 2 + 1];
    float2 f0 = __half22float2(acc[0]);
    float2 f1 = __half22float2(acc[1]);
    float2 f2 = __half22float2(acc[2]);
    float2 f3 = __half22float2(acc[3]);
    float xf[8];
    xf[0] = fmaf(dn, f0.x, bA.x); xf[1] = fmaf(dn, f0.y, bA.y);
    xf[2] = fmaf(dn, f1.x, bA.z); xf[3] = fmaf(dn, f1.y, bA.w);
    xf[4] = fmaf(dn, f2.x, bB.x); xf[5] = fmaf(dn, f2.y, bB.y);
    xf[6] = fmaf(dn, f3.x, bB.z); xf[7] = fmaf(dn, f3.y, bB.w);
    #pragma unroll
    for (int i = 0; i < 8; ++i) xf[i] = xf[i] > 0.f ? xf[i] : LEAKY * xf[i];
    // lane (eo,q) computes h2 cols [eo*4, eo*4+4) over features [q*8, q*8+8)
    float p0 = 0.f, p1 = 0.f, p2 = 0.f, p3 = 0.f;
    #pragma unroll
    for (int f = 0; f < 8; ++f) {
        f32x4 wv = *(const f32x4*)&sw[f * 256 + eo * 64 + q * 4];
        p0 = fmaf(xf[f], wv[0], p0);
        p1 = fmaf(xf[f], wv[1], p1);
        p2 = fmaf(xf[f], wv[2], p2);
        p3 = fmaf(xf[f], wv[3], p3);
    }
    #pragma unroll
    for (int mm = 1; mm < 16; mm <<= 1) {   // reduce over 16 q-lanes
        p0 += __shfl_xor(p0, mm);
        p1 += __shfl_xor(p1, mm);
        p2 += __shfl_xor(p2, mm);
        p3 += __shfl_xor(p3, mm);
    }
    if (q == 0) {
        H4 w;
        w.h[0] = __floats2half2_rn(p0 * dn, p1 * dn);
        w.h[1] = __floats2half2_rn(p2 * dn, p3 * dn);
        ((float2*)out)[(size_t)n * 4 + eo] = w.f;
    }
}

// ---------------- prop16: 16 lanes/node, 2 slots x 8 lanes, 16 edges in flight ----------------
// h rows fp16 pre-scaled by dis[src]; output x2 = dis*leaky(dis*sum + b) (pre-scaled fp16)
__global__ __launch_bounds__(256) void prop16(
        const __half* __restrict__ h, const int* __restrict__ rowptr,
        const int* __restrict__ col, const float* __restrict__ dis,
        const float* __restrict__ bias, __half* __restrict__ outp, int N) {
    int t = blockIdx.x * 256 + threadIdx.x;
    int n = t >> 4;
    if (n >= N) return;
    int li = threadIdx.x & 15;
    int eo = li >> 3;
    int hq = li & 7;
    const int* __restrict__ h2i = (const int*)h;
    int beg = rowptr[n], end = rowptr[n + 1];
    __half2 acc = __float2half2_rn(0.f);
    int j = beg + eo;
    for (; j + 14 < end; j += 16) {     // 16 edges in flight per node
        H2 u0, u1, u2, u3, u4, u5, u6, u7;
        u0.i = h2i[(size_t)col[j]      * 8 + hq];
        u1.i = h2i[(size_t)col[j + 2]  * 8 + hq];
        u2.i = h2i[(size_t)col[j + 4]  * 8 + hq];
        u3.i = h2i[(size_t)col[j + 6]  * 8 + hq];
        u4.i = h2i[(size_t)col[j + 8]  * 8 + hq];
        u5.i = h2i[(size_t)col[j + 10] * 8 + hq];
        u6.i = h2i[(size_t)col[j + 12] * 8 + hq];
        u7.i = h2i[(size_t)col[j + 14] * 8 + hq];
        acc = __hadd2(acc, u0.h); acc = __hadd2(acc, u1.h);
        acc = __hadd2(acc, u2.h); acc = __hadd2(acc, u3.h);
        acc = __hadd2(acc, u4.h); acc = __hadd2(acc, u5.h);
        acc = __hadd2(acc, u6.h); acc = __hadd2(acc, u7.h);
    }
    for (; j + 6 < end; j += 8) {
        H2 u0, u1, u2, u3;
        u0.i = h2i[(size_t)col[j]     * 8 + hq];
        u1.i = h2i[(size_t)col[j + 2] * 8 + hq];
        u2.i = h2i[(size_t)col[j + 4] * 8 + hq];
        u3.i = h2i[(size_t)col[j + 6] * 8 + hq];
        acc = __hadd2(acc, u0.h); acc = __hadd2(acc, u1.h);
        acc = __hadd2(acc, u2.h); acc = __hadd2(acc, u3.h);
    }
    for (; j < end; j += 2) {
        H2 u; u.i = h2i[(size_t)col[j] * 8 + hq];
        acc = __hadd2(acc, u.h);
    }
    acc = __hadd2(acc, shfl_xor_h2(acc, 8));
    if (eo == 0) {
        float dn = dis[n];
        float2 f = __half22float2(acc);
        float ox = fmaf(dn, f.x, bias[hq * 2]);
        float oy = fmaf(dn, f.y, bias[hq * 2 + 1]);
        ox = ox > 0.f ? ox : LEAKY * ox;
        oy = oy > 0.f ? oy : LEAKY * oy;
        ox *= dn; oy *= dn;
        H2 w; w.h = __floats2half2_rn(ox, oy);
        ((int*)outp)[(size_t)n * 8 + hq] = w.i;
    }
}

// ---------------- prop16_gemm3: gather x2 -> p3 (registers) -> @W3 + b3 -> out ----------------
__global__ __launch_bounds__(256) void prop16_gemm3(
        const __half* __restrict__ h, const int* __restrict__ rowptr,
        const int* __restrict__ col, const float* __restrict__ dis,
        const float* __restrict__ W3, const float* __restrict__ b3,
        float* __restrict__ out, int N) {
    __shared__ float sw[640];
    __shared__ float sb[40];
    int t0 = threadIdx.x;
    for (int i = t0; i < 640; i += 256) sw[i] = W3[i];
    if (t0 < 40) sb[t0] = b3[t0];
    __syncthreads();
    int t = blockIdx.x * 256 + t0;
    int n = t >> 4;
    if (n >= N) return;
    int li = t0 & 15;
    int eo = li >> 3;
    int hq = li & 7;
    const int* __restrict__ h2i = (const int*)h;
    int beg = rowptr[n], end = rowptr[n + 1];
    __half2 acc = __float2half2_rn(0.f);
    int j = beg + eo;
    for (; j + 14 < end; j += 16) {
        H2 u0, u1, u2, u3, u4, u5, u6, u7;
        u0.i = h2i[(size_t)col[j]      * 8 + hq];
        u1.i = h2i[(size_t)col[j + 2]  * 8 + hq];
        u2.i = h2i[(size_t)col[j + 4]  * 8 + hq];
        u3.i = h2i[(size_t)col[j + 6]  * 8 + hq];
        u4.i = h2i[(size_t)col[j + 8]  * 8 + hq];
        u5.i = h2i[(size_t)col[j + 10] * 8 + hq];
        u6.i = h2i[(size_t)col[j + 12] * 8 + hq];
        u7.i = h2i[(size_t)col[j + 14] * 8 + hq];
        acc = __hadd2(acc, u0.h); acc = __hadd2(acc, u1.h);
        acc = __hadd2(acc, u2.h); acc = __hadd2(acc, u3.h);
        acc = __hadd2(acc, u4.h); acc = __hadd2(acc, u5.h);
        acc = __hadd2(acc, u6.h); acc = __hadd2(acc, u7.h);
    }
    for (; j + 6 < end; j += 8) {
        H2 u0, u1, u2, u3;
        u0.i = h2i[(size_t)col[j]     * 8 + hq];
        u1.i = h2i[(size_t)col[j + 2] * 8 + hq];
        u2.i = h2i[(size_t)col[j + 4] * 8 + hq];
        u3.i = h2i[(size_t)col[j + 6] * 8 + hq];
        acc = __hadd2(acc, u0.h); acc = __hadd2(acc, u1.h);
        acc = __hadd2(acc, u2.h); acc = __hadd2(acc, u3.h);
    }
    for (; j < end; j += 2) {
        H2 u; u.i = h2i[(size_t)col[j] * 8 + hq];
        acc = __hadd2(acc, u.h);
    }
    acc = __hadd2(acc, shfl_xor_h2(acc, 8));
    // every lane now holds full p3 fragment for its hq (both eo copies identical)
    float dn = dis[n];
    int slot = (t0 & 63) & ~15;          // wave-lane base of this 16-lane slot
    H2 av; av.h = acc;
    float oA = 0.f, oB = 0.f, oC = 0.f;  // cols li, li+16, li+32
    #pragma unroll
    for (int hh = 0; hh < 8; ++hh) {
        H2 u; u.i = __shfl(av.i, slot + hh);
        float2 p = __half22float2(u.h);
        float p0 = dn * p.x, p1 = dn * p.y;
        int k0 = hh * 2;
        oA = fmaf(p0, sw[k0 * 40 + li],            oA);
        oA = fmaf(p1, sw[(k0 + 1) * 40 + li],      oA);
        oB = fmaf(p0, sw[k0 * 40 + li + 16],       oB);
        oB = fmaf(p1, sw[(k0 + 1) * 40 + li + 16], oB);
        if (li < 8) {
            oC = fmaf(p0, sw[k0 * 40 + li + 32],       oC);
            oC = fmaf(p1, sw[(k0 + 1) * 40 + li + 32], oC);
        }
    }
    float* orow = out + (size_t)n * 40;
    orow[li]      = oA + sb[li];
    orow[li + 16] = oB + sb[li + 16];
    if (li < 8) orow[li + 32] = oC + sb[li + 32];
}

// ---------------- launch ----------------

extern "C" void kernel_launch(void* const* d_in, const int* in_sizes, int n_in,
                              void* d_out, int out_size, void* d_ws, size_t ws_size,
                              hipStream_t stream) {
    const float* x  = (const float*)d_in[0];
    const int*   ei = (const int*)d_in[1];
    const float* W1 = (const float*)d_in[2];
    const float* b1 = (const float*)d_in[3];
    const float* W2 = (const float*)d_in[4];
    const float* b2 = (const float*)d_in[5];
    const float* W3 = (const float*)d_in[6];
    const float* b3 = (const float*)d_in[7];
    float* out = (float*)d_out;

    int N = in_sizes[0] / 256;   // 100000
    int E = in_sizes[1] / 2;     // 3200000
    const int* src = ei;
    const int* dst = ei + E;
    int NBUK = (N + BSZ - 1) >> BP;   // 1563

    char* w = (char*)d_ws;
    auto alloc = [&](size_t bytes) {
        char* p = w;
        w += (bytes + 255) & ~(size_t)255;
        return p;
    };
    int*    rowptr  = (int*)   alloc((size_t)(N + 1) * 4);
    int*    bhist   = (int*)   alloc((size_t)NBUK * 4);
    int*    bbase   = (int*)   alloc((size_t)(NBUK + 1) * 4);
    int*    bcur    = (int*)   alloc((size_t)NBUK * 4);
    int*    bhB     = (int*)   alloc((size_t)256 * NBUK * 4);
    int*    ebuf    = (int*)   alloc((size_t)E * 4);
    int*    colx    = (int*)   alloc((size_t)(E + N) * 4);
    float*  dis     = (float*) alloc((size_t)N * 4);
    __half* W1t     = (__half*)alloc((size_t)128 * 256 * 2);
    __half* h1h     = (__half*)alloc((size_t)N * 128 * 2);
    __half* h2h     = (__half*)alloc((size_t)N * 16 * 2);
    __half* x2h     = (__half*)alloc((size_t)N * 16 * 2);

    int SC_BLOCKS = 256;
    int chunk = (E + SC_BLOCKS - 1) / SC_BLOCKS;

    (void)hipMemsetAsync(bhist, 0, (size_t)NBUK * 4, stream);
    kinit   <<<384, 256, 0, stream>>>(dst, bhist, bhB, E, NBUK, chunk, W1, W1t);
    bscan   <<<1, 1024, 0, stream>>>(bhist, bbase, bcur, NBUK);
    kscatter2<<<SC_BLOCKS, 256, 0, stream>>>(src, dst, bcur, bhB, ebuf, E, NBUK, chunk);
    kbuild  <<<NBUK, 256, 0, stream>>>(ebuf, bbase, rowptr, dis, colx, N);

    int gtiles = (N + 63) / 64;
    gemm1_mfma<<<gtiles, 256, 0, stream>>>(x, W1t, dis, h1h, N);
    prop128g2 <<<(N * 64 + 255) / 256, 256, 0, stream>>>(h1h, rowptr, colx,
                                                         dis, b1, W2, h2h, N);
    prop16    <<<(N * 16 + 255) / 256, 256, 0, stream>>>(h2h, rowptr, colx,
                                                         dis, b2, x2h, N);
    prop16_gemm3<<<(N * 16 + 255) / 256, 256, 0, stream>>>(x2h, rowptr, colx,
                                                           dis, W3, b3, out, N);
}

// Round 10
// 517.182 us; speedup vs baseline: 1.5916x; 1.0124x over previous
//
#include <hip/hip_runtime.h>
#include <hip/hip_fp16.h>
#include <math.h>

#define LEAKY 0.2f
#define BP 6                     // nodes per bucket = 64
#define BSZ 64
#define NBUK_MAX 2048

typedef _Float16 f16x8 __attribute__((ext_vector_type(8)));
typedef float f32x4 __attribute__((ext_vector_type(4)));

union H2 { __half2 h; int i; };
union H8 { __half2 h[4]; float4 f; };
union H4 { __half2 h[2]; float2 f; };

__device__ inline __half2 shfl_xor_h2(__half2 v, int m) {
    H2 u; u.h = v;
    u.i = __shfl_xor(u.i, m);
    return u.h;
}

// ---------------- kinit: chunked khist (blocks 0..255, persists per-block hist)
// ----------------        + W1 transpose (256..383) ----------------
__global__ __launch_bounds__(256) void kinit(const int* __restrict__ dst,
                                             int* __restrict__ bhist,
                                             int* __restrict__ bhB,
                                             int E, int nbuk, int chunk,
                                             const float* __restrict__ W1,
                                             __half* __restrict__ W1t) {
    if (blockIdx.x < 256) {
        __shared__ int hist[NBUK_MAX];
        int t = threadIdx.x;
        for (int i = t; i < nbuk; i += 256) hist[i] = 0;
        __syncthreads();
        int base = blockIdx.x * chunk;
        int end = min(base + chunk, E);
        for (int e = base + t; e < end; e += 256)
            atomicAdd(&hist[dst[e] >> BP], 1);
        __syncthreads();
        int* myrow = bhB + (size_t)blockIdx.x * nbuk;
        for (int i = t; i < nbuk; i += 256) {
            int v = hist[i];
            myrow[i] = v;                       // persist for kscatter2
            if (v) atomicAdd(&bhist[i], v);
        }
    } else {
        int idx = (blockIdx.x - 256) * 256 + threadIdx.x;
        if (idx < 32768) {
            int n = idx >> 8, k = idx & 255;              // W1t[128][256]
            W1t[idx] = __float2half(W1[k * 128 + n]);
        }
    }
}

// single-block exclusive scan of bucket counts -> bbase, bcur
__global__ __launch_bounds__(1024) void bscan(const int* __restrict__ bhist,
                                              int* __restrict__ bbase,
                                              int* __restrict__ bcur, int nbuk) {
    __shared__ int s[1024];
    int t = threadIdx.x;
    int v[4]; int sum = 0;
    #pragma unroll
    for (int i = 0; i < 4; ++i) {
        int idx = t * 4 + i;
        v[i] = (idx < nbuk) ? bhist[idx] : 0;
        sum += v[i];
    }
    s[t] = sum; __syncthreads();
    for (int off = 1; off < 1024; off <<= 1) {
        int a = (t >= off) ? s[t - off] : 0;
        __syncthreads();
        s[t] += a;
        __syncthreads();
    }
    int run = (t > 0) ? s[t - 1] : 0;
    #pragma unroll
    for (int i = 0; i < 4; ++i) {
        int idx = t * 4 + i;
        if (idx < nbuk) { bbase[idx] = run; bcur[idx] = run; run += v[i]; }
    }
    if (t == 1023) bbase[nbuk] = s[1023];
}

// binning scatter: per-block hist precomputed by kinit (no recount pass)
__global__ __launch_bounds__(256) void kscatter2(const int* __restrict__ src,
                                                 const int* __restrict__ dst,
                                                 int* __restrict__ bcur,
                                                 const int* __restrict__ bhB,
                                                 int* __restrict__ ebuf,
                                                 int E, int nbuk, int chunk) {
    __shared__ int hist[NBUK_MAX];
    int t = threadIdx.x;
    int base = blockIdx.x * chunk;
    int end = min(base + chunk, E);
    const int* myrow = bhB + (size_t)blockIdx.x * nbuk;
    for (int i = t; i < nbuk; i += 256) {
        int c = myrow[i];
        hist[i] = c ? atomicAdd(&bcur[i], c) : 0;
    }
    __syncthreads();
    for (int e = base + t; e < end; e += 256) {
        int d = dst[e];
        int pos = atomicAdd(&hist[d >> BP], 1);
        ebuf[pos] = ((d & (BSZ - 1)) << 17) | src[e];
    }
}

// merged count+scan+place: per-bucket counts -> rowptr + dis, then place into col.
// Second ebuf pass hits L1/L2 (avg bucket = 8 KB).
__global__ __launch_bounds__(256) void kbuild(const int* __restrict__ ebuf,
                                              const int* __restrict__ bbase,
                                              int* __restrict__ rowptr,
                                              float* __restrict__ dis,
                                              int* __restrict__ col, int N) {
    __shared__ int h[BSZ];
    __shared__ int cur[BSZ];
    int b = blockIdx.x, t = threadIdx.x;
    if (t < BSZ) h[t] = 0;
    __syncthreads();
    int beg = bbase[b], end = bbase[b + 1];
    for (int j = beg + t; j < end; j += 256)
        atomicAdd(&h[(ebuf[j] >> 17) & (BSZ - 1)], 1);
    __syncthreads();
    if (t < BSZ) {                      // threads 0..63 = wave 0
        int node = b * BSZ + t;
        int c = (node < N) ? h[t] + 1 : 0;   // +1 self-loop
        int incl = c;
        #pragma unroll
        for (int off = 1; off < 64; off <<= 1) {
            int v = __shfl_up(incl, off);
            if (t >= off) incl += v;
        }
        int colbase = beg + b * BSZ;
        if (node < N) {
            int r = colbase + incl - c;
            rowptr[node] = r;
            dis[node] = rsqrtf((float)c);
            col[r] = node;              // self-loop first
            cur[t] = r + 1;
            if (node == N - 1) rowptr[N] = colbase + incl;
        }
    }
    __syncthreads();
    for (int j = beg + t; j < end; j += 256) {
        int v = ebuf[j];
        int p = atomicAdd(&cur[(v >> 17) & (BSZ - 1)], 1);
        col[p] = v & 0x1FFFF;
    }
}

// ---------------- GEMM1: [M,256]fp32 @ W1t[128,256]fp16 -> fp16, *= dis[row] ----------------
__global__ __launch_bounds__(256) void gemm1_mfma(
        const float* __restrict__ x, const __half* __restrict__ W1t,
        const float* __restrict__ dis, __half* __restrict__ C, int M) {
    int wave = threadIdx.x >> 6;
    int lane = threadIdx.x & 63;
    int m = lane & 15, q = lane >> 4;
    int row0 = (blockIdx.x * 4 + wave) * 16;
    int arow = row0 + m;
    bool aval = arow < M;
    const float* xr = x + (size_t)arow * 256 + q * 8;
    f32x4 acc[8];
    #pragma unroll
    for (int c = 0; c < 8; ++c) acc[c] = (f32x4){0.f, 0.f, 0.f, 0.f};
    for (int k0 = 0; k0 < 256; k0 += 32) {
        f16x8 a;
        if (aval) {
            float4 v0 = *(const float4*)(xr + k0);
            float4 v1 = *(const float4*)(xr + k0 + 4);
            a[0] = (_Float16)v0.x; a[1] = (_Float16)v0.y;
            a[2] = (_Float16)v0.z; a[3] = (_Float16)v0.w;
            a[4] = (_Float16)v1.x; a[5] = (_Float16)v1.y;
            a[6] = (_Float16)v1.z; a[7] = (_Float16)v1.w;
        } else {
            #pragma unroll
            for (int i = 0; i < 8; ++i) a[i] = (_Float16)0.f;
        }
        #pragma unroll
        for (int c = 0; c < 8; ++c) {
            f16x8 b = *(const f16x8*)(W1t + (size_t)(c * 16 + m) * 256 + k0 + q * 8);
            acc[c] = __builtin_amdgcn_mfma_f32_16x16x32_f16(a, b, acc[c], 0, 0, 0);
        }
    }
    float dw[4];
    #pragma unroll
    for (int r = 0; r < 4; ++r) {
        int rr = row0 + q * 4 + r;
        dw[r] = (rr < M) ? dis[rr] : 0.f;
    }
    #pragma unroll
    for (int c = 0; c < 8; ++c) {
        #pragma unroll
        for (int r = 0; r < 4; ++r) {
            int rr = row0 + q * 4 + r;
            if (rr < M)
                C[(size_t)rr * 128 + c * 16 + m] = __float2half(acc[c][r] * dw[r]);
        }
    }
}

// ---------------- prop128g2: aggregate h1 (128 fp16) + fused layer-2 GEMM epilogue ----------------
// out = h2h[n][16] = dis[n] * ( leaky(dis[n]*sum + b1) @ W2 )
// W2 staged in LDS, layout sw[f*256 + eo*64 + q*4 + j] = W2[(q*8+f)*16 + eo*4 + j].
// Staging writes are LINEAR (conflict-free); permutation applied to the global
// source index (W2 is 8 KB, L1-resident -> scattered reads cheap).
__global__ __launch_bounds__(256) void prop128g2(
        const __half* __restrict__ h, const int* __restrict__ rowptr,
        const int* __restrict__ col, const float* __restrict__ dis,
        const float* __restrict__ bias, const float* __restrict__ W2,
        __half* __restrict__ out, int N) {
    __shared__ float sw[2048];              // 8 KB, exact
    for (int k = threadIdx.x; k < 2048; k += 256) {
        int f  = k >> 8;                    // 0..7
        int r  = k & 255;
        int e2 = r >> 6;                    // 0..3
        int qq = (r >> 2) & 15;             // 0..15
        int jj = r & 3;
        sw[k] = W2[(qq * 8 + f) * 16 + e2 * 4 + jj];
    }
    __syncthreads();

    int n = (blockIdx.x * 256 + threadIdx.x) >> 6;
    if (n >= N) return;
    int lane = threadIdx.x & 63;
    int eo = lane >> 4;
    int q = lane & 15;
    const float4* __restrict__ h4 = (const float4*)h;
    int beg = rowptr[n], end = rowptr[n + 1];
    __half2 acc[4];
    acc[0] = acc[1] = acc[2] = acc[3] = __float2half2_rn(0.f);
    int j = beg + eo;
    for (; j + 28 < end; j += 32) {     // 32 edges in flight per wave
        int s0 = col[j],      s1 = col[j + 4],  s2 = col[j + 8],  s3 = col[j + 12];
        int s4 = col[j + 16], s5 = col[j + 20], s6 = col[j + 24], s7 = col[j + 28];
        H8 u0, u1, u2, u3, u4, u5, u6, u7;
        u0.f = h4[(size_t)s0 * 16 + q];
        u1.f = h4[(size_t)s1 * 16 + q];
        u2.f = h4[(size_t)s2 * 16 + q];
        u3.f = h4[(size_t)s3 * 16 + q];
        u4.f = h4[(size_t)s4 * 16 + q];
        u5.f = h4[(size_t)s5 * 16 + q];
        u6.f = h4[(size_t)s6 * 16 + q];
        u7.f = h4[(size_t)s7 * 16 + q];
        #pragma unroll
        for (int i = 0; i < 4; ++i) acc[i] = __hadd2(acc[i], u0.h[i]);
        #pragma unroll
        for (int i = 0; i < 4; ++i) acc[i] = __hadd2(acc[i], u1.h[i]);
        #pragma unroll
        for (int i = 0; i < 4; ++i) acc[i] = __hadd2(acc[i], u2.h[i]);
        #pragma unroll
        for (int i = 0; i < 4; ++i) acc[i] = __hadd2(acc[i], u3.h[i]);
        #pragma unroll
        for (int i = 0; i < 4; ++i) acc[i] = __hadd2(acc[i], u4.h[i]);
        #pragma unroll
        for (int i = 0; i < 4; ++i) acc[i] = __hadd2(acc[i], u5.h[i]);
        #pragma unroll
        for (int i = 0; i < 4; ++i) acc[i] = __hadd2(acc[i], u6.h[i]);
        #pragma unroll
        for (int i = 0; i < 4; ++i) acc[i] = __hadd2(acc[i], u7.h[i]);
    }
    for (; j + 12 < end; j += 16) {
        int s0 = col[j], s1 = col[j + 4], s2 = col[j + 8], s3 = col[j + 12];
        H8 u0, u1, u2, u3;
        u0.f = h4[(size_t)s0 * 16 + q];
        u1.f = h4[(size_t)s1 * 16 + q];
        u2.f = h4[(size_t)s2 * 16 + q];
        u3.f = h4[(size_t)s3 * 16 + q];
        #pragma unroll
        for (int i = 0; i < 4; ++i) acc[i] = __hadd2(acc[i], u0.h[i]);
        #pragma unroll
        for (int i = 0; i < 4; ++i) acc[i] = __hadd2(acc[i], u1.h[i]);
        #pragma unroll
        for (int i = 0; i < 4; ++i) acc[i] = __hadd2(acc[i], u2.h[i]);
        #pragma unroll
        for (int i = 0; i < 4; ++i) acc[i] = __hadd2(acc[i], u3.h[i]);
    }
    for (; j + 4 < end; j += 8) {
        int s0 = col[j], s1 = col[j + 4];
        H8 u0, u1;
        u0.f = h4[(size_t)s0 * 16 + q];
        u1.f = h4[(size_t)s1 * 16 + q];
        #pragma unroll
        for (int i = 0; i < 4; ++i) acc[i] = __hadd2(acc[i], u0.h[i]);
        #pragma unroll
        for (int i = 0; i < 4; ++i) acc[i] = __hadd2(acc[i], u1.h[i]);
    }
    for (; j < end; j += 4) {
        int s = col[j];
        H8 u; u.f = h4[(size_t)s * 16 + q];
        #pragma unroll
        for (int i = 0; i < 4; ++i) acc[i] = __hadd2(acc[i], u.h[i]);
    }
    #pragma unroll
    for (int i = 0; i < 4; ++i) {
        acc[i] = __hadd2(acc[i], shfl_xor_h2(acc[i], 16));
        acc[i] = __hadd2(acc[i], shfl_xor_h2(acc[i], 32));
    }
    // --- fused epilogue: x1 row fragment (8 feats q*8..q*8+7) in every lane -> @W2 ---
    float dn = dis[n];
    const float4* b4 = (const float4*)bias;
    float4 bA = b4[q * 2];
    float4 bB = b4[q * 2 + 1];
    float2 f0 = __half22float2(acc[0]);
    float2 f1 = __half22float2(acc[1]);
    float2 f2 = __half22float2(acc[2]);
    float2 f3 = __half22float2(acc[3]);
    float xf[8];
    xf[0] = fmaf(dn, f0.x, bA.x); xf[1] = fmaf(dn, f0.y, bA.y);
    xf[2] = fmaf(dn, f1.x, bA.z); xf[3] = fmaf(dn, f1.y, bA.w);
    xf[4] = fmaf(dn, f2.x, bB.x); xf[5] = fmaf(dn, f2.y, bB.y);
    xf[6] = fmaf(dn, f3.x, bB.z); xf[7] = fmaf(dn, f3.y, bB.w);
    #pragma unroll
    for (int i = 0; i < 8; ++i) xf[i] = xf[i] > 0.f ? xf[i] : LEAKY * xf[i];
    // lane (eo,q) computes h2 cols [eo*4, eo*4+4) over features [q*8, q*8+8)
    float p0 = 0.f, p1 = 0.f, p2 = 0.f, p3 = 0.f;
    #pragma unroll
    for (int f = 0; f < 8; ++f) {
        f32x4 wv = *(const f32x4*)&sw[f * 256 + eo * 64 + q * 4];
        p0 = fmaf(xf[f], wv[0], p0);
        p1 = fmaf(xf[f], wv[1], p1);
        p2 = fmaf(xf[f], wv[2], p2);
        p3 = fmaf(xf[f], wv[3], p3);
    }
    #pragma unroll
    for (int mm = 1; mm < 16; mm <<= 1) {   // reduce over 16 q-lanes
        p0 += __shfl_xor(p0, mm);
        p1 += __shfl_xor(p1, mm);
        p2 += __shfl_xor(p2, mm);
        p3 += __shfl_xor(p3, mm);
    }
    if (q == 0) {
        H4 w;
        w.h[0] = __floats2half2_rn(p0 * dn, p1 * dn);
        w.h[1] = __floats2half2_rn(p2 * dn, p3 * dn);
        ((float2*)out)[(size_t)n * 4 + eo] = w.f;
    }
}

// ---------------- prop16: 8 lanes/node, float4 gathers (2 lanes/row), 16 edges in flight ----------------
// h rows fp16 pre-scaled by dis[src]; output x2 = dis*leaky(dis*sum + b) (pre-scaled fp16)
__global__ __launch_bounds__(256) void prop16(
        const __half* __restrict__ h, const int* __restrict__ rowptr,
        const int* __restrict__ col, const float* __restrict__ dis,
        const float* __restrict__ bias, __half* __restrict__ outp, int N) {
    int t = blockIdx.x * 256 + threadIdx.x;
    int n = t >> 3;
    if (n >= N) return;
    int li = threadIdx.x & 7;
    int slot = li >> 1;                  // 0..3 edge slot
    int half = li & 1;                   // 0..1 half-row (16 B)
    const float4* __restrict__ h4 = (const float4*)h;
    int beg = rowptr[n], end = rowptr[n + 1];
    __half2 acc[4];
    acc[0] = acc[1] = acc[2] = acc[3] = __float2half2_rn(0.f);
    int j = beg + slot;
    for (; j + 12 < end; j += 16) {      // 16 edges in flight per node
        int s0 = col[j], s1 = col[j + 4], s2 = col[j + 8], s3 = col[j + 12];
        H8 u0, u1, u2, u3;
        u0.f = h4[(size_t)s0 * 2 + half];
        u1.f = h4[(size_t)s1 * 2 + half];
        u2.f = h4[(size_t)s2 * 2 + half];
        u3.f = h4[(size_t)s3 * 2 + half];
        #pragma unroll
        for (int i = 0; i < 4; ++i) acc[i] = __hadd2(acc[i], u0.h[i]);
        #pragma unroll
        for (int i = 0; i < 4; ++i) acc[i] = __hadd2(acc[i], u1.h[i]);
        #pragma unroll
        for (int i = 0; i < 4; ++i) acc[i] = __hadd2(acc[i], u2.h[i]);
        #pragma unroll
        for (int i = 0; i < 4; ++i) acc[i] = __hadd2(acc[i], u3.h[i]);
    }
    for (; j + 4 < end; j += 8) {
        int s0 = col[j], s1 = col[j + 4];
        H8 u0, u1;
        u0.f = h4[(size_t)s0 * 2 + half];
        u1.f = h4[(size_t)s1 * 2 + half];
        #pragma unroll
        for (int i = 0; i < 4; ++i) acc[i] = __hadd2(acc[i], u0.h[i]);
        #pragma unroll
        for (int i = 0; i < 4; ++i) acc[i] = __hadd2(acc[i], u1.h[i]);
    }
    for (; j < end; j += 4) {
        int s = col[j];
        H8 u; u.f = h4[(size_t)s * 2 + half];
        #pragma unroll
        for (int i = 0; i < 4; ++i) acc[i] = __hadd2(acc[i], u.h[i]);
    }
    // reduce over 4 slots (same half): xor 2, xor 4
    #pragma unroll
    for (int i = 0; i < 4; ++i) {
        acc[i] = __hadd2(acc[i], shfl_xor_h2(acc[i], 2));
        acc[i] = __hadd2(acc[i], shfl_xor_h2(acc[i], 4));
    }
    if (slot == 0) {                     // lanes li in {0,1}: full sums for their half
        float dn = dis[n];
        const float4* b4 = (const float4*)bias;
        float4 bA = b4[half * 2];
        float4 bB = b4[half * 2 + 1];
        float2 f0 = __half22float2(acc[0]);
        float2 f1 = __half22float2(acc[1]);
        float2 f2 = __half22float2(acc[2]);
        float2 f3 = __half22float2(acc[3]);
        float o0 = fmaf(dn, f0.x, bA.x), o1 = fmaf(dn, f0.y, bA.y);
        float o2 = fmaf(dn, f1.x, bA.z), o3 = fmaf(dn, f1.y, bA.w);
        float o4 = fmaf(dn, f2.x, bB.x), o5 = fmaf(dn, f2.y, bB.y);
        float o6 = fmaf(dn, f3.x, bB.z), o7 = fmaf(dn, f3.y, bB.w);
        o0 = o0 > 0.f ? o0 : LEAKY * o0;  o1 = o1 > 0.f ? o1 : LEAKY * o1;
        o2 = o2 > 0.f ? o2 : LEAKY * o2;  o3 = o3 > 0.f ? o3 : LEAKY * o3;
        o4 = o4 > 0.f ? o4 : LEAKY * o4;  o5 = o5 > 0.f ? o5 : LEAKY * o5;
        o6 = o6 > 0.f ? o6 : LEAKY * o6;  o7 = o7 > 0.f ? o7 : LEAKY * o7;
        o0 *= dn; o1 *= dn; o2 *= dn; o3 *= dn;
        o4 *= dn; o5 *= dn; o6 *= dn; o7 *= dn;
        H8 w;
        w.h[0] = __floats2half2_rn(o0, o1);
        w.h[1] = __floats2half2_rn(o2, o3);
        w.h[2] = __floats2half2_rn(o4, o5);
        w.h[3] = __floats2half2_rn(o6, o7);
        ((float4*)outp)[(size_t)n * 2 + half] = w.f;
    }
}

// ---------------- prop16_gemm3: 8 lanes/node float4 gather -> p3 -> @W3 + b3 -> out ----------------
__global__ __launch_bounds__(256) void prop16_gemm3(
        const __half* __restrict__ h, const int* __restrict__ rowptr,
        const int* __restrict__ col, const float* __restrict__ dis,
        const float* __restrict__ W3, const float* __restrict__ b3,
        float* __restrict__ out, int N) {
    __shared__ float sw[640];
    __shared__ float sb[40];
    int t0 = threadIdx.x;
    for (int i = t0; i < 640; i += 256) sw[i] = W3[i];
    if (t0 < 40) sb[t0] = b3[t0];
    __syncthreads();
    int t = blockIdx.x * 256 + t0;
    int n = t >> 3;
    if (n >= N) return;
    int li = t0 & 7;
    int slot = li >> 1;
    int half = li & 1;
    const float4* __restrict__ h4 = (const float4*)h;
    int beg = rowptr[n], end = rowptr[n + 1];
    __half2 acc[4];
    acc[0] = acc[1] = acc[2] = acc[3] = __float2half2_rn(0.f);
    int j = beg + slot;
    for (; j + 12 < end; j += 16) {
        int s0 = col[j], s1 = col[j + 4], s2 = col[j + 8], s3 = col[j + 12];
        H8 u0, u1, u2, u3;
        u0.f = h4[(size_t)s0 * 2 + half];
        u1.f = h4[(size_t)s1 * 2 + half];
        u2.f = h4[(size_t)s2 * 2 + half];
        u3.f = h4[(size_t)s3 * 2 + half];
        #pragma unroll
        for (int i = 0; i < 4; ++i) acc[i] = __hadd2(acc[i], u0.h[i]);
        #pragma unroll
        for (int i = 0; i < 4; ++i) acc[i] = __hadd2(acc[i], u1.h[i]);
        #pragma unroll
        for (int i = 0; i < 4; ++i) acc[i] = __hadd2(acc[i], u2.h[i]);
        #pragma unroll
        for (int i = 0; i < 4; ++i) acc[i] = __hadd2(acc[i], u3.h[i]);
    }
    for (; j + 4 < end; j += 8) {
        int s0 = col[j], s1 = col[j + 4];
        H8 u0, u1;
        u0.f = h4[(size_t)s0 * 2 + half];
        u1.f = h4[(size_t)s1 * 2 + half];
        #pragma unroll
        for (int i = 0; i < 4; ++i) acc[i] = __hadd2(acc[i], u0.h[i]);
        #pragma unroll
        for (int i = 0; i < 4; ++i) acc[i] = __hadd2(acc[i], u1.h[i]);
    }
    for (; j < end; j += 4) {
        int s = col[j];
        H8 u; u.f = h4[(size_t)s * 2 + half];
        #pragma unroll
        for (int i = 0; i < 4; ++i) acc[i] = __hadd2(acc[i], u.h[i]);
    }
    // reduce over 4 slots: xor 2, xor 4
    #pragma unroll
    for (int i = 0; i < 4; ++i) {
        acc[i] = __hadd2(acc[i], shfl_xor_h2(acc[i], 2));
        acc[i] = __hadd2(acc[i], shfl_xor_h2(acc[i], 4));
    }
    // exchange halves: every lane assembles the full 16-feature row
    __half2 oth[4];
    #pragma unroll
    for (int i = 0; i < 4; ++i) oth[i] = shfl_xor_h2(acc[i], 1);
    float dn = dis[n];
    float p[16];
    #pragma unroll
    for (int i = 0; i < 4; ++i) {
        __half2 lo = half ? oth[i] : acc[i];     // features 0..7
        __half2 hi = half ? acc[i] : oth[i];     // features 8..15
        float2 a = __half22float2(lo);
        float2 b = __half22float2(hi);
        p[2 * i]     = dn * a.x;  p[2 * i + 1]     = dn * a.y;
        p[8 + 2 * i] = dn * b.x;  p[8 + 2 * i + 1] = dn * b.y;
    }
    float o0 = 0.f, o1 = 0.f, o2 = 0.f, o3 = 0.f, o4 = 0.f;
    #pragma unroll
    for (int k = 0; k < 16; ++k) {
        const float* wr = &sw[k * 40 + li];
        o0 = fmaf(p[k], wr[0],  o0);
        o1 = fmaf(p[k], wr[8],  o1);
        o2 = fmaf(p[k], wr[16], o2);
        o3 = fmaf(p[k], wr[24], o3);
        o4 = fmaf(p[k], wr[32], o4);
    }
    float* orow = out + (size_t)n * 40;
    orow[li]      = o0 + sb[li];
    orow[li + 8]  = o1 + sb[li + 8];
    orow[li + 16] = o2 + sb[li + 16];
    orow[li + 24] = o3 + sb[li + 24];
    orow[li + 32] = o4 + sb[li + 32];
}

// ---------------- launch ----------------

extern "C" void kernel_launch(void* const* d_in, const int* in_sizes, int n_in,
                              void* d_out, int out_size, void* d_ws, size_t ws_size,
                              hipStream_t stream) {
    const float* x  = (const float*)d_in[0];
    const int*   ei = (const int*)d_in[1];
    const float* W1 = (const float*)d_in[2];
    const float* b1 = (const float*)d_in[3];
    const float* W2 = (const float*)d_in[4];
    const float* b2 = (const float*)d_in[5];
    const float* W3 = (const float*)d_in[6];
    const float* b3 = (const float*)d_in[7];
    float* out = (float*)d_out;

    int N = in_sizes[0] / 256;   // 100000
    int E = in_sizes[1] / 2;     // 3200000
    const int* src = ei;
    const int* dst = ei + E;
    int NBUK = (N + BSZ - 1) >> BP;   // 1563

    char* w = (char*)d_ws;
    auto alloc = [&](size_t bytes) {
        char* p = w;
        w += (bytes + 255) & ~(size_t)255;
        return p;
    };
    int*    rowptr  = (int*)   alloc((size_t)(N + 1) * 4);
    int*    bhist   = (int*)   alloc((size_t)NBUK * 4);
    int*    bbase   = (int*)   alloc((size_t)(NBUK + 1) * 4);
    int*    bcur    = (int*)   alloc((size_t)NBUK * 4);
    int*    bhB     = (int*)   alloc((size_t)256 * NBUK * 4);
    int*    ebuf    = (int*)   alloc((size_t)E * 4);
    int*    colx    = (int*)   alloc((size_t)(E + N) * 4);
    float*  dis     = (float*) alloc((size_t)N * 4);
    __half* W1t     = (__half*)alloc((size_t)128 * 256 * 2);
    __half* h1h     = (__half*)alloc((size_t)N * 128 * 2);
    __half* h2h     = (__half*)alloc((size_t)N * 16 * 2);
    __half* x2h     = (__half*)alloc((size_t)N * 16 * 2);

    int SC_BLOCKS = 256;
    int chunk = (E + SC_BLOCKS - 1) / SC_BLOCKS;

    (void)hipMemsetAsync(bhist, 0, (size_t)NBUK * 4, stream);
    kinit   <<<384, 256, 0, stream>>>(dst, bhist, bhB, E, NBUK, chunk, W1, W1t);
    bscan   <<<1, 1024, 0, stream>>>(bhist, bbase, bcur, NBUK);
    kscatter2<<<SC_BLOCKS, 256, 0, stream>>>(src, dst, bcur, bhB, ebuf, E, NBUK, chunk);
    kbuild  <<<NBUK, 256, 0, stream>>>(ebuf, bbase, rowptr, dis, colx, N);

    int gtiles = (N + 63) / 64;
    gemm1_mfma<<<gtiles, 256, 0, stream>>>(x, W1t, dis, h1h, N);
    prop128g2 <<<(N * 64 + 255) / 256, 256, 0, stream>>>(h1h, rowptr, colx,
                                                         dis, b1, W2, h2h, N);
    prop16    <<<(N * 8 + 255) / 256, 256, 0, stream>>>(h2h, rowptr, colx,
                                                        dis, b2, x2h, N);
    prop16_gemm3<<<(N * 8 + 255) / 256, 256, 0, stream>>>(x2h, rowptr, colx,
                                                          dis, W3, b3, out, N);
}

// Round 11
// 509.736 us; speedup vs baseline: 1.6149x; 1.0146x over previous
//
#include <hip/hip_runtime.h>
#include <hip/hip_fp16.h>
#include <math.h>

#define LEAKY 0.2f
#define BP 6                     // nodes per bucket = 64
#define BSZ 64
#define NBUK_MAX 2048

typedef _Float16 f16x8 __attribute__((ext_vector_type(8)));
typedef _Float16 f16x2 __attribute__((ext_vector_type(2)));
typedef float f32x4 __attribute__((ext_vector_type(4)));

union H2 { __half2 h; f16x2 f; int i; };
union H8 { __half2 h[4]; float4 f; };
union H4 { __half2 h[2]; float2 f; };

__device__ inline __half2 shfl_xor_h2(__half2 v, int m) {
    H2 u; u.h = v;
    u.i = __shfl_xor(u.i, m);
    return u.h;
}

// ---------------- kinit: chunked khist (blocks 0..255, persists per-block hist)
// ---------------- + W1 transpose + W2 fp16 pair-pack (256..383) ----------------
__global__ __launch_bounds__(256) void kinit(const int* __restrict__ dst,
                                             int* __restrict__ bhist,
                                             int* __restrict__ bhB,
                                             int E, int nbuk, int chunk,
                                             const float* __restrict__ W1,
                                             __half* __restrict__ W1t,
                                             const float* __restrict__ W2,
                                             __half2* __restrict__ W2h2) {
    if (blockIdx.x < 256) {
        __shared__ int hist[NBUK_MAX];
        int t = threadIdx.x;
        for (int i = t; i < nbuk; i += 256) hist[i] = 0;
        __syncthreads();
        int base = blockIdx.x * chunk;
        int end = min(base + chunk, E);
        for (int e = base + t; e < end; e += 256)
            atomicAdd(&hist[dst[e] >> BP], 1);
        __syncthreads();
        int* myrow = bhB + (size_t)blockIdx.x * nbuk;
        for (int i = t; i < nbuk; i += 256) {
            int v = hist[i];
            myrow[i] = v;                       // persist for kscatter2
            if (v) atomicAdd(&bhist[i], v);
        }
    } else {
        int idx = (blockIdx.x - 256) * 256 + threadIdx.x;
        if (idx < 32768) {
            int n = idx >> 8, k = idx & 255;              // W1t[128][256]
            W1t[idx] = __float2half(W1[k * 128 + n]);
        }
        if (idx < 1024) {
            // W2h2[fp*256 + e2*64 + qq*4 + jj] =
            //   ( W2[(qq*8+2fp)*16 + e2*4+jj], W2[(qq*8+2fp+1)*16 + e2*4+jj] )
            int fp = idx >> 8;
            int r  = idx & 255;
            int e2 = r >> 6;
            int qq = (r >> 2) & 15;
            int jj = r & 3;
            float lo = W2[(qq * 8 + 2 * fp)     * 16 + e2 * 4 + jj];
            float hi = W2[(qq * 8 + 2 * fp + 1) * 16 + e2 * 4 + jj];
            W2h2[idx] = __floats2half2_rn(lo, hi);
        }
    }
}

// single-block exclusive scan of bucket counts -> bbase, bcur
__global__ __launch_bounds__(1024) void bscan(const int* __restrict__ bhist,
                                              int* __restrict__ bbase,
                                              int* __restrict__ bcur, int nbuk) {
    __shared__ int s[1024];
    int t = threadIdx.x;
    int v[4]; int sum = 0;
    #pragma unroll
    for (int i = 0; i < 4; ++i) {
        int idx = t * 4 + i;
        v[i] = (idx < nbuk) ? bhist[idx] : 0;
        sum += v[i];
    }
    s[t] = sum; __syncthreads();
    for (int off = 1; off < 1024; off <<= 1) {
        int a = (t >= off) ? s[t - off] : 0;
        __syncthreads();
        s[t] += a;
        __syncthreads();
    }
    int run = (t > 0) ? s[t - 1] : 0;
    #pragma unroll
    for (int i = 0; i < 4; ++i) {
        int idx = t * 4 + i;
        if (idx < nbuk) { bbase[idx] = run; bcur[idx] = run; run += v[i]; }
    }
    if (t == 1023) bbase[nbuk] = s[1023];
}

// binning scatter: per-block hist precomputed by kinit (no recount pass)
__global__ __launch_bounds__(256) void kscatter2(const int* __restrict__ src,
                                                 const int* __restrict__ dst,
                                                 int* __restrict__ bcur,
                                                 const int* __restrict__ bhB,
                                                 int* __restrict__ ebuf,
                                                 int E, int nbuk, int chunk) {
    __shared__ int hist[NBUK_MAX];
    int t = threadIdx.x;
    int base = blockIdx.x * chunk;
    int end = min(base + chunk, E);
    const int* myrow = bhB + (size_t)blockIdx.x * nbuk;
    for (int i = t; i < nbuk; i += 256) {
        int c = myrow[i];
        hist[i] = c ? atomicAdd(&bcur[i], c) : 0;
    }
    __syncthreads();
    for (int e = base + t; e < end; e += 256) {
        int d = dst[e];
        int pos = atomicAdd(&hist[d >> BP], 1);
        ebuf[pos] = ((d & (BSZ - 1)) << 17) | src[e];
    }
}

// merged count+scan+place: per-bucket counts -> rowptr + dis, then place into col.
// Second ebuf pass hits L1/L2 (avg bucket = 8 KB).
__global__ __launch_bounds__(256) void kbuild(const int* __restrict__ ebuf,
                                              const int* __restrict__ bbase,
                                              int* __restrict__ rowptr,
                                              float* __restrict__ dis,
                                              int* __restrict__ col, int N) {
    __shared__ int h[BSZ];
    __shared__ int cur[BSZ];
    int b = blockIdx.x, t = threadIdx.x;
    if (t < BSZ) h[t] = 0;
    __syncthreads();
    int beg = bbase[b], end = bbase[b + 1];
    for (int j = beg + t; j < end; j += 256)
        atomicAdd(&h[(ebuf[j] >> 17) & (BSZ - 1)], 1);
    __syncthreads();
    if (t < BSZ) {                      // threads 0..63 = wave 0
        int node = b * BSZ + t;
        int c = (node < N) ? h[t] + 1 : 0;   // +1 self-loop
        int incl = c;
        #pragma unroll
        for (int off = 1; off < 64; off <<= 1) {
            int v = __shfl_up(incl, off);
            if (t >= off) incl += v;
        }
        int colbase = beg + b * BSZ;
        if (node < N) {
            int r = colbase + incl - c;
            rowptr[node] = r;
            dis[node] = rsqrtf((float)c);
            col[r] = node;              // self-loop first
            cur[t] = r + 1;
            if (node == N - 1) rowptr[N] = colbase + incl;
        }
    }
    __syncthreads();
    for (int j = beg + t; j < end; j += 256) {
        int v = ebuf[j];
        int p = atomicAdd(&cur[(v >> 17) & (BSZ - 1)], 1);
        col[p] = v & 0x1FFFF;
    }
}

// ---------------- GEMM1: [M,256]fp32 @ W1t[128,256]fp16 -> fp16, *= dis[row] ----------------
__global__ __launch_bounds__(256) void gemm1_mfma(
        const float* __restrict__ x, const __half* __restrict__ W1t,
        const float* __restrict__ dis, __half* __restrict__ C, int M) {
    int wave = threadIdx.x >> 6;
    int lane = threadIdx.x & 63;
    int m = lane & 15, q = lane >> 4;
    int row0 = (blockIdx.x * 4 + wave) * 16;
    int arow = row0 + m;
    bool aval = arow < M;
    const float* xr = x + (size_t)arow * 256 + q * 8;
    f32x4 acc[8];
    #pragma unroll
    for (int c = 0; c < 8; ++c) acc[c] = (f32x4){0.f, 0.f, 0.f, 0.f};
    for (int k0 = 0; k0 < 256; k0 += 32) {
        f16x8 a;
        if (aval) {
            float4 v0 = *(const float4*)(xr + k0);
            float4 v1 = *(const float4*)(xr + k0 + 4);
            a[0] = (_Float16)v0.x; a[1] = (_Float16)v0.y;
            a[2] = (_Float16)v0.z; a[3] = (_Float16)v0.w;
            a[4] = (_Float16)v1.x; a[5] = (_Float16)v1.y;
            a[6] = (_Float16)v1.z; a[7] = (_Float16)v1.w;
        } else {
            #pragma unroll
            for (int i = 0; i < 8; ++i) a[i] = (_Float16)0.f;
        }
        #pragma unroll
        for (int c = 0; c < 8; ++c) {
            f16x8 b = *(const f16x8*)(W1t + (size_t)(c * 16 + m) * 256 + k0 + q * 8);
            acc[c] = __builtin_amdgcn_mfma_f32_16x16x32_f16(a, b, acc[c], 0, 0, 0);
        }
    }
    float dw[4];
    #pragma unroll
    for (int r = 0; r < 4; ++r) {
        int rr = row0 + q * 4 + r;
        dw[r] = (rr < M) ? dis[rr] : 0.f;
    }
    #pragma unroll
    for (int c = 0; c < 8; ++c) {
        #pragma unroll
        for (int r = 0; r < 4; ++r) {
            int rr = row0 + q * 4 + r;
            if (rr < M)
                C[(size_t)rr * 128 + c * 16 + m] = __float2half(acc[c][r] * dw[r]);
        }
    }
}

// ---------------- prop128g2: aggregate h1 (128 fp16) + fused layer-2 GEMM epilogue ----------------
// out = h2h[n][16] = dis[n] * ( leaky(dis[n]*sum + b1) @ W2 )
// W2 staged in LDS as fp16 feature-PAIRS (4 KB, pre-packed by kinit, linear staging);
// product via v_dot2_f32_f16: 16 dot2 + 4 ds_read_b128 per lane (was 32 FMA + 8 reads).
__global__ __launch_bounds__(256) void prop128g2(
        const __half* __restrict__ h, const int* __restrict__ rowptr,
        const int* __restrict__ col, const float* __restrict__ dis,
        const float* __restrict__ bias, const __half2* __restrict__ W2h2,
        __half* __restrict__ out, int N) {
    __shared__ __half2 swh[1024];           // 4 KB
    {
        int k = threadIdx.x;                // 256 threads x 16 B = 4 KB
        ((float4*)swh)[k] = ((const float4*)W2h2)[k];
    }
    __syncthreads();

    int n = (blockIdx.x * 256 + threadIdx.x) >> 6;
    if (n >= N) return;
    int lane = threadIdx.x & 63;
    int eo = lane >> 4;
    int q = lane & 15;
    const float4* __restrict__ h4 = (const float4*)h;
    int beg = rowptr[n], end = rowptr[n + 1];
    __half2 acc[4];
    acc[0] = acc[1] = acc[2] = acc[3] = __float2half2_rn(0.f);
    int j = beg + eo;
    for (; j + 28 < end; j += 32) {     // 32 edges in flight per wave
        int s0 = col[j],      s1 = col[j + 4],  s2 = col[j + 8],  s3 = col[j + 12];
        int s4 = col[j + 16], s5 = col[j + 20], s6 = col[j + 24], s7 = col[j + 28];
        H8 u0, u1, u2, u3, u4, u5, u6, u7;
        u0.f = h4[(size_t)s0 * 16 + q];
        u1.f = h4[(size_t)s1 * 16 + q];
        u2.f = h4[(size_t)s2 * 16 + q];
        u3.f = h4[(size_t)s3 * 16 + q];
        u4.f = h4[(size_t)s4 * 16 + q];
        u5.f = h4[(size_t)s5 * 16 + q];
        u6.f = h4[(size_t)s6 * 16 + q];
        u7.f = h4[(size_t)s7 * 16 + q];
        #pragma unroll
        for (int i = 0; i < 4; ++i) acc[i] = __hadd2(acc[i], u0.h[i]);
        #pragma unroll
        for (int i = 0; i < 4; ++i) acc[i] = __hadd2(acc[i], u1.h[i]);
        #pragma unroll
        for (int i = 0; i < 4; ++i) acc[i] = __hadd2(acc[i], u2.h[i]);
        #pragma unroll
        for (int i = 0; i < 4; ++i) acc[i] = __hadd2(acc[i], u3.h[i]);
        #pragma unroll
        for (int i = 0; i < 4; ++i) acc[i] = __hadd2(acc[i], u4.h[i]);
        #pragma unroll
        for (int i = 0; i < 4; ++i) acc[i] = __hadd2(acc[i], u5.h[i]);
        #pragma unroll
        for (int i = 0; i < 4; ++i) acc[i] = __hadd2(acc[i], u6.h[i]);
        #pragma unroll
        for (int i = 0; i < 4; ++i) acc[i] = __hadd2(acc[i], u7.h[i]);
    }
    for (; j + 12 < end; j += 16) {
        int s0 = col[j], s1 = col[j + 4], s2 = col[j + 8], s3 = col[j + 12];
        H8 u0, u1, u2, u3;
        u0.f = h4[(size_t)s0 * 16 + q];
        u1.f = h4[(size_t)s1 * 16 + q];
        u2.f = h4[(size_t)s2 * 16 + q];
        u3.f = h4[(size_t)s3 * 16 + q];
        #pragma unroll
        for (int i = 0; i < 4; ++i) acc[i] = __hadd2(acc[i], u0.h[i]);
        #pragma unroll
        for (int i = 0; i < 4; ++i) acc[i] = __hadd2(acc[i], u1.h[i]);
        #pragma unroll
        for (int i = 0; i < 4; ++i) acc[i] = __hadd2(acc[i], u2.h[i]);
        #pragma unroll
        for (int i = 0; i < 4; ++i) acc[i] = __hadd2(acc[i], u3.h[i]);
    }
    for (; j + 4 < end; j += 8) {
        int s0 = col[j], s1 = col[j + 4];
        H8 u0, u1;
        u0.f = h4[(size_t)s0 * 16 + q];
        u1.f = h4[(size_t)s1 * 16 + q];
        #pragma unroll
        for (int i = 0; i < 4; ++i) acc[i] = __hadd2(acc[i], u0.h[i]);
        #pragma unroll
        for (int i = 0; i < 4; ++i) acc[i] = __hadd2(acc[i], u1.h[i]);
    }
    for (; j < end; j += 4) {
        int s = col[j];
        H8 u; u.f = h4[(size_t)s * 16 + q];
        #pragma unroll
        for (int i = 0; i < 4; ++i) acc[i] = __hadd2(acc[i], u.h[i]);
    }
    #pragma unroll
    for (int i = 0; i < 4; ++i) {
        acc[i] = __hadd2(acc[i], shfl_xor_h2(acc[i], 16));
        acc[i] = __hadd2(acc[i], shfl_xor_h2(acc[i], 32));
    }
    // --- fused epilogue: x1 row fragment (8 feats q*8..q*8+7) in every lane -> @W2 ---
    float dn = dis[n];
    const float4* b4 = (const float4*)bias;
    float4 bA = b4[q * 2];
    float4 bB = b4[q * 2 + 1];
    float2 f0 = __half22float2(acc[0]);
    float2 f1 = __half22float2(acc[1]);
    float2 f2 = __half22float2(acc[2]);
    float2 f3 = __half22float2(acc[3]);
    float xf[8];
    xf[0] = fmaf(dn, f0.x, bA.x); xf[1] = fmaf(dn, f0.y, bA.y);
    xf[2] = fmaf(dn, f1.x, bA.z); xf[3] = fmaf(dn, f1.y, bA.w);
    xf[4] = fmaf(dn, f2.x, bB.x); xf[5] = fmaf(dn, f2.y, bB.y);
    xf[6] = fmaf(dn, f3.x, bB.z); xf[7] = fmaf(dn, f3.y, bB.w);
    #pragma unroll
    for (int i = 0; i < 8; ++i) xf[i] = xf[i] > 0.f ? xf[i] : LEAKY * xf[i];
    // pack xf into fp16 pairs (matches baseline x1h-fp16 numerics)
    H2 xh[4];
    #pragma unroll
    for (int fp = 0; fp < 4; ++fp)
        xh[fp].h = __floats2half2_rn(xf[2 * fp], xf[2 * fp + 1]);
    // lane (eo,q) computes h2 cols [eo*4, eo*4+4) over features [q*8, q*8+8)
    float p0 = 0.f, p1 = 0.f, p2 = 0.f, p3 = 0.f;
    #pragma unroll
    for (int fp = 0; fp < 4; ++fp) {
        H8 wv;                           // 4 half2 = cols eo*4..+3 of feature-pair fp
        wv.f = *(const float4*)&swh[fp * 256 + eo * 64 + q * 4];
        H2 w0, w1, w2, w3;
        w0.h = wv.h[0]; w1.h = wv.h[1]; w2.h = wv.h[2]; w3.h = wv.h[3];
        p0 = __builtin_amdgcn_fdot2(xh[fp].f, w0.f, p0, false);
        p1 = __builtin_amdgcn_fdot2(xh[fp].f, w1.f, p1, false);
        p2 = __builtin_amdgcn_fdot2(xh[fp].f, w2.f, p2, false);
        p3 = __builtin_amdgcn_fdot2(xh[fp].f, w3.f, p3, false);
    }
    #pragma unroll
    for (int mm = 1; mm < 16; mm <<= 1) {   // reduce over 16 q-lanes
        p0 += __shfl_xor(p0, mm);
        p1 += __shfl_xor(p1, mm);
        p2 += __shfl_xor(p2, mm);
        p3 += __shfl_xor(p3, mm);
    }
    if (q == 0) {
        H4 w;
        w.h[0] = __floats2half2_rn(p0 * dn, p1 * dn);
        w.h[1] = __floats2half2_rn(p2 * dn, p3 * dn);
        ((float2*)out)[(size_t)n * 4 + eo] = w.f;
    }
}

// ---------------- prop16: 8 lanes/node, float4 gathers (2 lanes/row), 16 edges in flight ----------------
// h rows fp16 pre-scaled by dis[src]; output x2 = dis*leaky(dis*sum + b) (pre-scaled fp16)
__global__ __launch_bounds__(256) void prop16(
        const __half* __restrict__ h, const int* __restrict__ rowptr,
        const int* __restrict__ col, const float* __restrict__ dis,
        const float* __restrict__ bias, __half* __restrict__ outp, int N) {
    int t = blockIdx.x * 256 + threadIdx.x;
    int n = t >> 3;
    if (n >= N) return;
    int li = threadIdx.x & 7;
    int slot = li >> 1;                  // 0..3 edge slot
    int half = li & 1;                   // 0..1 half-row (16 B)
    const float4* __restrict__ h4 = (const float4*)h;
    int beg = rowptr[n], end = rowptr[n + 1];
    __half2 acc[4];
    acc[0] = acc[1] = acc[2] = acc[3] = __float2half2_rn(0.f);
    int j = beg + slot;
    for (; j + 12 < end; j += 16) {      // 16 edges in flight per node
        int s0 = col[j], s1 = col[j + 4], s2 = col[j + 8], s3 = col[j + 12];
        H8 u0, u1, u2, u3;
        u0.f = h4[(size_t)s0 * 2 + half];
        u1.f = h4[(size_t)s1 * 2 + half];
        u2.f = h4[(size_t)s2 * 2 + half];
        u3.f = h4[(size_t)s3 * 2 + half];
        #pragma unroll
        for (int i = 0; i < 4; ++i) acc[i] = __hadd2(acc[i], u0.h[i]);
        #pragma unroll
        for (int i = 0; i < 4; ++i) acc[i] = __hadd2(acc[i], u1.h[i]);
        #pragma unroll
        for (int i = 0; i < 4; ++i) acc[i] = __hadd2(acc[i], u2.h[i]);
        #pragma unroll
        for (int i = 0; i < 4; ++i) acc[i] = __hadd2(acc[i], u3.h[i]);
    }
    for (; j + 4 < end; j += 8) {
        int s0 = col[j], s1 = col[j + 4];
        H8 u0, u1;
        u0.f = h4[(size_t)s0 * 2 + half];
        u1.f = h4[(size_t)s1 * 2 + half];
        #pragma unroll
        for (int i = 0; i < 4; ++i) acc[i] = __hadd2(acc[i], u0.h[i]);
        #pragma unroll
        for (int i = 0; i < 4; ++i) acc[i] = __hadd2(acc[i], u1.h[i]);
    }
    for (; j < end; j += 4) {
        int s = col[j];
        H8 u; u.f = h4[(size_t)s * 2 + half];
        #pragma unroll
        for (int i = 0; i < 4; ++i) acc[i] = __hadd2(acc[i], u.h[i]);
    }
    // reduce over 4 slots (same half): xor 2, xor 4
    #pragma unroll
    for (int i = 0; i < 4; ++i) {
        acc[i] = __hadd2(acc[i], shfl_xor_h2(acc[i], 2));
        acc[i] = __hadd2(acc[i], shfl_xor_h2(acc[i], 4));
    }
    if (slot == 0) {                     // lanes li in {0,1}: full sums for their half
        float dn = dis[n];
        const float4* b4 = (const float4*)bias;
        float4 bA = b4[half * 2];
        float4 bB = b4[half * 2 + 1];
        float2 f0 = __half22float2(acc[0]);
        float2 f1 = __half22float2(acc[1]);
        float2 f2 = __half22float2(acc[2]);
        float2 f3 = __half22float2(acc[3]);
        float o0 = fmaf(dn, f0.x, bA.x), o1 = fmaf(dn, f0.y, bA.y);
        float o2 = fmaf(dn, f1.x, bA.z), o3 = fmaf(dn, f1.y, bA.w);
        float o4 = fmaf(dn, f2.x, bB.x), o5 = fmaf(dn, f2.y, bB.y);
        float o6 = fmaf(dn, f3.x, bB.z), o7 = fmaf(dn, f3.y, bB.w);
        o0 = o0 > 0.f ? o0 : LEAKY * o0;  o1 = o1 > 0.f ? o1 : LEAKY * o1;
        o2 = o2 > 0.f ? o2 : LEAKY * o2;  o3 = o3 > 0.f ? o3 : LEAKY * o3;
        o4 = o4 > 0.f ? o4 : LEAKY * o4;  o5 = o5 > 0.f ? o5 : LEAKY * o5;
        o6 = o6 > 0.f ? o6 : LEAKY * o6;  o7 = o7 > 0.f ? o7 : LEAKY * o7;
        o0 *= dn; o1 *= dn; o2 *= dn; o3 *= dn;
        o4 *= dn; o5 *= dn; o6 *= dn; o7 *= dn;
        H8 w;
        w.h[0] = __floats2half2_rn(o0, o1);
        w.h[1] = __floats2half2_rn(o2, o3);
        w.h[2] = __floats2half2_rn(o4, o5);
        w.h[3] = __floats2half2_rn(o6, o7);
        ((float4*)outp)[(size_t)n * 2 + half] = w.f;
    }
}

// ---------------- prop16_gemm3: 8 lanes/node float4 gather -> p3 -> @W3 + b3 -> out ----------------
__global__ __launch_bounds__(256) void prop16_gemm3(
        const __half* __restrict__ h, const int* __restrict__ rowptr,
        const int* __restrict__ col, const float* __restrict__ dis,
        const float* __restrict__ W3, const float* __restrict__ b3,
        float* __restrict__ out, int N) {
    __shared__ float sw[640];
    __shared__ float sb[40];
    int t0 = threadIdx.x;
    for (int i = t0; i < 640; i += 256) sw[i] = W3[i];
    if (t0 < 40) sb[t0] = b3[t0];
    __syncthreads();
    int t = blockIdx.x * 256 + t0;
    int n = t >> 3;
    if (n >= N) return;
    int li = t0 & 7;
    int slot = li >> 1;
    int half = li & 1;
    const float4* __restrict__ h4 = (const float4*)h;
    int beg = rowptr[n], end = rowptr[n + 1];
    __half2 acc[4];
    acc[0] = acc[1] = acc[2] = acc[3] = __float2half2_rn(0.f);
    int j = beg + slot;
    for (; j + 12 < end; j += 16) {
        int s0 = col[j], s1 = col[j + 4], s2 = col[j + 8], s3 = col[j + 12];
        H8 u0, u1, u2, u3;
        u0.f = h4[(size_t)s0 * 2 + half];
        u1.f = h4[(size_t)s1 * 2 + half];
        u2.f = h4[(size_t)s2 * 2 + half];
        u3.f = h4[(size_t)s3 * 2 + half];
        #pragma unroll
        for (int i = 0; i < 4; ++i) acc[i] = __hadd2(acc[i], u0.h[i]);
        #pragma unroll
        for (int i = 0; i < 4; ++i) acc[i] = __hadd2(acc[i], u1.h[i]);
        #pragma unroll
        for (int i = 0; i < 4; ++i) acc[i] = __hadd2(acc[i], u2.h[i]);
        #pragma unroll
        for (int i = 0; i < 4; ++i) acc[i] = __hadd2(acc[i], u3.h[i]);
    }
    for (; j + 4 < end; j += 8) {
        int s0 = col[j], s1 = col[j + 4];
        H8 u0, u1;
        u0.f = h4[(size_t)s0 * 2 + half];
        u1.f = h4[(size_t)s1 * 2 + half];
        #pragma unroll
        for (int i = 0; i < 4; ++i) acc[i] = __hadd2(acc[i], u0.h[i]);
        #pragma unroll
        for (int i = 0; i < 4; ++i) acc[i] = __hadd2(acc[i], u1.h[i]);
    }
    for (; j < end; j += 4) {
        int s = col[j];
        H8 u; u.f = h4[(size_t)s * 2 + half];
        #pragma unroll
        for (int i = 0; i < 4; ++i) acc[i] = __hadd2(acc[i], u.h[i]);
    }
    // reduce over 4 slots: xor 2, xor 4
    #pragma unroll
    for (int i = 0; i < 4; ++i) {
        acc[i] = __hadd2(acc[i], shfl_xor_h2(acc[i], 2));
        acc[i] = __hadd2(acc[i], shfl_xor_h2(acc[i], 4));
    }
    // exchange halves: every lane assembles the full 16-feature row
    __half2 oth[4];
    #pragma unroll
    for (int i = 0; i < 4; ++i) oth[i] = shfl_xor_h2(acc[i], 1);
    float dn = dis[n];
    float p[16];
    #pragma unroll
    for (int i = 0; i < 4; ++i) {
        __half2 lo = half ? oth[i] : acc[i];     // features 0..7
        __half2 hi = half ? acc[i] : oth[i];     // features 8..15
        float2 a = __half22float2(lo);
        float2 b = __half22float2(hi);
        p[2 * i]     = dn * a.x;  p[2 * i + 1]     = dn * a.y;
        p[8 + 2 * i] = dn * b.x;  p[8 + 2 * i + 1] = dn * b.y;
    }
    float o0 = 0.f, o1 = 0.f, o2 = 0.f, o3 = 0.f, o4 = 0.f;
    #pragma unroll
    for (int k = 0; k < 16; ++k) {
        const float* wr = &sw[k * 40 + li];
        o0 = fmaf(p[k], wr[0],  o0);
        o1 = fmaf(p[k], wr[8],  o1);
        o2 = fmaf(p[k], wr[16], o2);
        o3 = fmaf(p[k], wr[24], o3);
        o4 = fmaf(p[k], wr[32], o4);
    }
    float* orow = out + (size_t)n * 40;
    orow[li]      = o0 + sb[li];
    orow[li + 8]  = o1 + sb[li + 8];
    orow[li + 16] = o2 + sb[li + 16];
    orow[li + 24] = o3 + sb[li + 24];
    orow[li + 32] = o4 + sb[li + 32];
}

// ---------------- launch ----------------

extern "C" void kernel_launch(void* const* d_in, const int* in_sizes, int n_in,
                              void* d_out, int out_size, void* d_ws, size_t ws_size,
                              hipStream_t stream) {
    const float* x  = (const float*)d_in[0];
    const int*   ei = (const int*)d_in[1];
    const float* W1 = (const float*)d_in[2];
    const float* b1 = (const float*)d_in[3];
    const float* W2 = (const float*)d_in[4];
    const float* b2 = (const float*)d_in[5];
    const float* W3 = (const float*)d_in[6];
    const float* b3 = (const float*)d_in[7];
    float* out = (float*)d_out;

    int N = in_sizes[0] / 256;   // 100000
    int E = in_sizes[1] / 2;     // 3200000
    const int* src = ei;
    const int* dst = ei + E;
    int NBUK = (N + BSZ - 1) >> BP;   // 1563

    char* w = (char*)d_ws;
    auto alloc = [&](size_t bytes) {
        char* p = w;
        w += (bytes + 255) & ~(size_t)255;
        return p;
    };
    int*     rowptr  = (int*)    alloc((size_t)(N + 1) * 4);
    int*     bhist   = (int*)    alloc((size_t)NBUK * 4);
    int*     bbase   = (int*)    alloc((size_t)(NBUK + 1) * 4);
    int*     bcur    = (int*)    alloc((size_t)NBUK * 4);
    int*     bhB     = (int*)    alloc((size_t)256 * NBUK * 4);
    int*     ebuf    = (int*)    alloc((size_t)E * 4);
    int*     colx    = (int*)    alloc((size_t)(E + N) * 4);
    float*   dis     = (float*)  alloc((size_t)N * 4);
    __half*  W1t     = (__half*) alloc((size_t)128 * 256 * 2);
    __half2* W2h2    = (__half2*)alloc((size_t)1024 * 4);
    __half*  h1h     = (__half*) alloc((size_t)N * 128 * 2);
    __half*  h2h     = (__half*) alloc((size_t)N * 16 * 2);
    __half*  x2h     = (__half*) alloc((size_t)N * 16 * 2);

    int SC_BLOCKS = 256;
    int chunk = (E + SC_BLOCKS - 1) / SC_BLOCKS;

    (void)hipMemsetAsync(bhist, 0, (size_t)NBUK * 4, stream);
    kinit   <<<384, 256, 0, stream>>>(dst, bhist, bhB, E, NBUK, chunk,
                                      W1, W1t, W2, W2h2);
    bscan   <<<1, 1024, 0, stream>>>(bhist, bbase, bcur, NBUK);
    kscatter2<<<SC_BLOCKS, 256, 0, stream>>>(src, dst, bcur, bhB, ebuf, E, NBUK, chunk);
    kbuild  <<<NBUK, 256, 0, stream>>>(ebuf, bbase, rowptr, dis, colx, N);

    int gtiles = (N + 63) / 64;
    gemm1_mfma<<<gtiles, 256, 0, stream>>>(x, W1t, dis, h1h, N);
    prop128g2 <<<(N * 64 + 255) / 256, 256, 0, stream>>>(h1h, rowptr, colx,
                                                         dis, b1, W2h2, h2h, N);
    prop16    <<<(N * 8 + 255) / 256, 256, 0, stream>>>(h2h, rowptr, colx,
                                                        dis, b2, x2h, N);
    prop16_gemm3<<<(N * 8 + 255) / 256, 256, 0, stream>>>(x2h, rowptr, colx,
                                                          dis, W3, b3, out, N);
}